// Round 4
// baseline (1208.400 us; speedup 1.0000x reference)
//
#include <hip/hip_runtime.h>
#include <math.h>

typedef unsigned int  u32;
typedef unsigned short u16;

__device__ inline u32 bf16_rne(float f) {
    u32 u = __float_as_uint(f);
    return (u + 0x7FFFu + ((u >> 16) & 1u)) >> 16;
}
__device__ inline float bf_lo(u32 u) { return __uint_as_float(u << 16); }
__device__ inline float bf_hi(u32 u) { return __uint_as_float(u & 0xFFFF0000u); }

// ================= CSR build =================

__global__ __launch_bounds__(256) void k_zero_int(int* p, int n) {
    int i = blockIdx.x * 256 + threadIdx.x;
    if (i < n) p[i] = 0;
}

__global__ __launch_bounds__(256) void k_count(const int* __restrict__ ei,
                                               int* __restrict__ cnt,
                                               int E, int N) {
    int i = blockIdx.x * 256 + threadIdx.x;
    if (i < E) {
        int d = ei[E + i];
        if ((unsigned)d < (unsigned)N) atomicAdd(&cnt[d], 1);
    }
}

__global__ __launch_bounds__(256) void k_chunk_sum(const int* __restrict__ cnt,
                                                   int* __restrict__ chunkSum,
                                                   int N) {
    __shared__ int red[256];
    int t = threadIdx.x;
    int i = blockIdx.x * 256 + t;
    red[t] = (i < N) ? cnt[i] : 0;
    __syncthreads();
    for (int off = 128; off > 0; off >>= 1) {
        if (t < off) red[t] += red[t + off];
        __syncthreads();
    }
    if (t == 0) chunkSum[blockIdx.x] = red[0];
}

__global__ __launch_bounds__(512) void k_scan_chunks(const int* __restrict__ chunkSum,
                                                     int* __restrict__ chunkOff,
                                                     int nchunk) {
    __shared__ int sc[512];
    int t = threadIdx.x;
    int v = (t < nchunk) ? chunkSum[t] : 0;
    sc[t] = v;
    __syncthreads();
    for (int off = 1; off < 512; off <<= 1) {
        int u = (t >= off) ? sc[t - off] : 0;
        __syncthreads();
        sc[t] += u;
        __syncthreads();
    }
    if (t < nchunk) chunkOff[t] = sc[t] - v;
}

__global__ __launch_bounds__(256) void k_write_rowptr(const int* __restrict__ cnt,
                                                      const int* __restrict__ chunkOff,
                                                      int* __restrict__ rowptr,
                                                      int* __restrict__ cursor,
                                                      int N, int E) {
    __shared__ int sc[256];
    int t = threadIdx.x;
    int i = blockIdx.x * 256 + t;
    int v = (i < N) ? cnt[i] : 0;
    sc[t] = v;
    __syncthreads();
    for (int off = 1; off < 256; off <<= 1) {
        int u = (t >= off) ? sc[t - off] : 0;
        __syncthreads();
        sc[t] += u;
        __syncthreads();
    }
    if (i < N) {
        int ex = chunkOff[blockIdx.x] + sc[t] - v;
        rowptr[i] = ex;
        cursor[i] = ex;
        if (i == N - 1) rowptr[N] = ex + v;
    }
}

// bucket cursors: bucket b = nodes [b*64, b*64+64); offset = rowptr[b*64]
__global__ __launch_bounds__(256) void k_bcur(const int* __restrict__ rowptr,
                                              int* __restrict__ bcur, int NB) {
    int b = blockIdx.x * 256 + threadIdx.x;
    if (b < NB) bcur[b] = rowptr[b << 6];
}

// pass B: append (src,dst) into bucket-ordered tmp (1563 write fronts -> L2 merge)
__global__ __launch_bounds__(256) void k_bucket(const int* __restrict__ ei,
                                                int* __restrict__ bcur,
                                                int2* __restrict__ tmp,
                                                int E, int N) {
    int i = blockIdx.x * 256 + threadIdx.x;
    if (i < E) {
        int s = ei[i];
        int d = ei[E + i];
        if ((unsigned)d < (unsigned)N) {
            int pos = atomicAdd(&bcur[d >> 6], 1);
            tmp[pos] = make_int2(s, d);
        }
    }
}

// pass C: place within bucket (writes localized to ~8KB csr windows)
__global__ __launch_bounds__(256) void k_place(const int2* __restrict__ tmp,
                                               int* __restrict__ cursor,
                                               int* __restrict__ csr, int E) {
    int i = blockIdx.x * 256 + threadIdx.x;
    if (i < E) {
        int2 e = tmp[i];
        int pos = atomicAdd(&cursor[e.y], 1);
        csr[pos] = e.x;
    }
}

__global__ __launch_bounds__(256) void k_dis(const int* __restrict__ rowptr,
                                             float* __restrict__ dis, int n) {
    int i = blockIdx.x * 256 + threadIdx.x;
    if (i < n) {
        float deg = (float)(rowptr[i + 1] - rowptr[i]) + 1.0f;
        dis[i] = rsqrtf(deg);
    }
}

// ========== GEMM: Hb = bf16( (X @ W) * dis[row] ), packed 2 cols/uint ==========

template <int BM, int BN, int TM, bool RELU_IN>
__global__ __launch_bounds__(256) void k_gemm(
    const float* __restrict__ X, const float* __restrict__ W,
    const float* __restrict__ dis, uint4* __restrict__ Hb, int M)
{
    constexpr int K = 128;
    constexpr int TN = 8;
    constexpr int RG = BM / TM;
    constexpr int LSTR = BM + 4;
    __shared__ float xs[K * LSTR];

    const int tid = threadIdx.x;
    const int m0 = blockIdx.x * BM;

    const float4* X4 = (const float4*)X;
    constexpr int NV = BM * (K / 4) / 256;
#pragma unroll
    for (int i = 0; i < NV; ++i) {
        int idx = tid + i * 256;
        int r = idx >> 5;
        int kq = idx & 31;
        float4 v = make_float4(0.f, 0.f, 0.f, 0.f);
        int gr = m0 + r;
        if (gr < M) v = X4[gr * 32 + kq];
        if (RELU_IN) {
            v.x = fmaxf(v.x, 0.f); v.y = fmaxf(v.y, 0.f);
            v.z = fmaxf(v.z, 0.f); v.w = fmaxf(v.w, 0.f);
        }
        int kb = kq * 4;
        xs[(kb + 0) * LSTR + r] = v.x;
        xs[(kb + 1) * LSTR + r] = v.y;
        xs[(kb + 2) * LSTR + r] = v.z;
        xs[(kb + 3) * LSTR + r] = v.w;
    }
    __syncthreads();

    const int rg = tid % RG;
    const int cg = tid / RG;

    float acc[TM][TN];
#pragma unroll
    for (int j = 0; j < TM; ++j)
#pragma unroll
        for (int c = 0; c < TN; ++c) acc[j][c] = 0.f;

    const float4* W4 = (const float4*)W;
#pragma unroll 4
    for (int k = 0; k < K; ++k) {
        float a[TM];
        if constexpr (TM == 4) {
            float4 av = *(const float4*)&xs[k * LSTR + rg * 4];
            a[0] = av.x; a[1] = av.y; a[2] = av.z; a[3] = av.w;
        } else {
            float2 av = *(const float2*)&xs[k * LSTR + rg * 2];
            a[0] = av.x; a[1] = av.y;
        }
        float4 b0 = W4[k * (BN / 4) + cg * 2];
        float4 b1 = W4[k * (BN / 4) + cg * 2 + 1];
#pragma unroll
        for (int j = 0; j < TM; ++j) {
            acc[j][0] = fmaf(a[j], b0.x, acc[j][0]);
            acc[j][1] = fmaf(a[j], b0.y, acc[j][1]);
            acc[j][2] = fmaf(a[j], b0.z, acc[j][2]);
            acc[j][3] = fmaf(a[j], b0.w, acc[j][3]);
            acc[j][4] = fmaf(a[j], b1.x, acc[j][4]);
            acc[j][5] = fmaf(a[j], b1.y, acc[j][5]);
            acc[j][6] = fmaf(a[j], b1.z, acc[j][6]);
            acc[j][7] = fmaf(a[j], b1.w, acc[j][7]);
        }
    }

#pragma unroll
    for (int j = 0; j < TM; ++j) {
        int r = m0 + rg * TM + j;
        if (r < M) {
            float dv = dis[r];
            uint4 p;
            p.x = bf16_rne(acc[j][0] * dv) | (bf16_rne(acc[j][1] * dv) << 16);
            p.y = bf16_rne(acc[j][2] * dv) | (bf16_rne(acc[j][3] * dv) << 16);
            p.z = bf16_rne(acc[j][4] * dv) | (bf16_rne(acc[j][5] * dv) << 16);
            p.w = bf16_rne(acc[j][6] * dv) | (bf16_rne(acc[j][7] * dv) << 16);
            Hb[r * (BN / 8) + cg] = p;
        }
    }
}

// ====== Aggregate L1 (D=128): AGG[n] = dn*(sum Hs[src] + Hs[n]) + bias ======
// one wave/node, lane reads 1 uint (bf16x2) per edge, unroll x8

__global__ __launch_bounds__(256) void k_agg1(
    const int* __restrict__ rowptr, const int* __restrict__ csr,
    const float* __restrict__ dis, const u32* __restrict__ Hb,
    const float* __restrict__ bias, float* __restrict__ AGG, int N)
{
    int n = (blockIdx.x * 256 + threadIdx.x) >> 6;
    int lane = threadIdx.x & 63;
    if (n >= N) return;
    int e = rowptr[n];
    const int s1 = rowptr[n + 1];
    const float dn = dis[n];

    float a0 = 0.f, a1 = 0.f, b0 = 0.f, b1 = 0.f;
    float c0 = 0.f, c1 = 0.f, d0 = 0.f, d1 = 0.f;

    for (; e + 8 <= s1; e += 8) {
        int i0 = csr[e + 0], i1 = csr[e + 1], i2 = csr[e + 2], i3 = csr[e + 3];
        int i4 = csr[e + 4], i5 = csr[e + 5], i6 = csr[e + 6], i7 = csr[e + 7];
        u32 u0 = Hb[i0 * 64 + lane], u1 = Hb[i1 * 64 + lane];
        u32 u2 = Hb[i2 * 64 + lane], u3 = Hb[i3 * 64 + lane];
        u32 u4 = Hb[i4 * 64 + lane], u5 = Hb[i5 * 64 + lane];
        u32 u6 = Hb[i6 * 64 + lane], u7 = Hb[i7 * 64 + lane];
        a0 += bf_lo(u0) + bf_lo(u4); a1 += bf_hi(u0) + bf_hi(u4);
        b0 += bf_lo(u1) + bf_lo(u5); b1 += bf_hi(u1) + bf_hi(u5);
        c0 += bf_lo(u2) + bf_lo(u6); c1 += bf_hi(u2) + bf_hi(u6);
        d0 += bf_lo(u3) + bf_lo(u7); d1 += bf_hi(u3) + bf_hi(u7);
    }
    for (; e < s1; ++e) {
        u32 u = Hb[csr[e] * 64 + lane];
        a0 += bf_lo(u); a1 += bf_hi(u);
    }

    u32 self = Hb[n * 64 + lane];
    float2 bv = ((const float2*)bias)[lane];
    float2 o;
    o.x = fmaf(dn, (a0 + b0) + (c0 + d0) + bf_lo(self), bv.x);
    o.y = fmaf(dn, (a1 + b1) + (c1 + d1) + bf_hi(self), bv.y);
    ((float2*)AGG)[n * 64 + lane] = o;
}

// ====== Aggregate L2 (D=64): lane reads 1 ushort (bf16) per edge ======

__global__ __launch_bounds__(256) void k_agg2(
    const int* __restrict__ rowptr, const int* __restrict__ csr,
    const float* __restrict__ dis, const u16* __restrict__ Hb,
    const float* __restrict__ bias, float* __restrict__ AGG, int N)
{
    int n = (blockIdx.x * 256 + threadIdx.x) >> 6;
    int lane = threadIdx.x & 63;
    if (n >= N) return;
    int e = rowptr[n];
    const int s1 = rowptr[n + 1];
    const float dn = dis[n];

    float a0 = 0.f, b0 = 0.f, c0 = 0.f, d0 = 0.f;

    for (; e + 8 <= s1; e += 8) {
        int i0 = csr[e + 0], i1 = csr[e + 1], i2 = csr[e + 2], i3 = csr[e + 3];
        int i4 = csr[e + 4], i5 = csr[e + 5], i6 = csr[e + 6], i7 = csr[e + 7];
        float v0 = __uint_as_float((u32)Hb[i0 * 64 + lane] << 16);
        float v1 = __uint_as_float((u32)Hb[i1 * 64 + lane] << 16);
        float v2 = __uint_as_float((u32)Hb[i2 * 64 + lane] << 16);
        float v3 = __uint_as_float((u32)Hb[i3 * 64 + lane] << 16);
        float v4 = __uint_as_float((u32)Hb[i4 * 64 + lane] << 16);
        float v5 = __uint_as_float((u32)Hb[i5 * 64 + lane] << 16);
        float v6 = __uint_as_float((u32)Hb[i6 * 64 + lane] << 16);
        float v7 = __uint_as_float((u32)Hb[i7 * 64 + lane] << 16);
        a0 += v0 + v4; b0 += v1 + v5; c0 += v2 + v6; d0 += v3 + v7;
    }
    for (; e < s1; ++e)
        a0 += __uint_as_float((u32)Hb[csr[e] * 64 + lane] << 16);

    float self = __uint_as_float((u32)Hb[n * 64 + lane] << 16);
    AGG[n * 64 + lane] = fmaf(dn, (a0 + b0) + (c0 + d0) + self, bias[lane]);
}

// ================= mean pool over sorted batch =================

__device__ inline int lower_bound(const int* __restrict__ b, int n, int v) {
    int lo = 0, hi = n;
    while (lo < hi) { int m = (lo + hi) >> 1; if (b[m] < v) lo = m + 1; else hi = m; }
    return lo;
}

__global__ __launch_bounds__(256) void k_pool(
    const int* __restrict__ batch, const float* __restrict__ AGG2,
    float* __restrict__ G, int n)
{
    int g = blockIdx.x;
    int start = lower_bound(batch, n, g);
    int end   = lower_bound(batch, n, g + 1);
    int tid = threadIdx.x;
    int f = tid & 63, stripe = tid >> 6;
    float acc = 0.f;
    for (int i = start + stripe; i < end; i += 4)
        acc += AGG2[(size_t)i * 64 + f];
    __shared__ float red[256];
    red[tid] = acc;
    __syncthreads();
    if (tid < 64) {
        float s = red[tid] + red[tid + 64] + red[tid + 128] + red[tid + 192];
        float c = (float)(end - start);
        G[g * 64 + tid] = s / fmaxf(c, 1.0f);
    }
}

// ================= classifier =================

__global__ __launch_bounds__(256) void k_fc(
    const float* __restrict__ G, const float* __restrict__ Wfc,
    const float* __restrict__ bfc, float* __restrict__ out, int ng)
{
    __shared__ float wl[640];
    __shared__ float bl[10];
    int tid = threadIdx.x;
    for (int i = tid; i < 640; i += 256) wl[i] = Wfc[i];
    if (tid < 10) bl[tid] = bfc[tid];
    __syncthreads();
    if (tid >= ng) return;
    float acc[10];
#pragma unroll
    for (int c = 0; c < 10; ++c) acc[c] = bl[c];
    for (int k = 0; k < 64; ++k) {
        float gv = G[tid * 64 + k];
#pragma unroll
        for (int c = 0; c < 10; ++c) acc[c] = fmaf(gv, wl[k * 10 + c], acc[c]);
    }
#pragma unroll
    for (int c = 0; c < 10; ++c) out[tid * 10 + c] = acc[c];
}

// ================= launch =================

extern "C" void kernel_launch(void* const* d_in, const int* in_sizes, int n_in,
                              void* d_out, int out_size, void* d_ws, size_t ws_size,
                              hipStream_t stream)
{
    const float* x    = (const float*)d_in[0];
    const int*   ei   = (const int*)d_in[1];
    const int*   batch= (const int*)d_in[2];
    const float* W1   = (const float*)d_in[3];
    const float* b1   = (const float*)d_in[4];
    const float* W2   = (const float*)d_in[5];
    const float* b2   = (const float*)d_in[6];
    const float* Wfc  = (const float*)d_in[7];
    const float* bfc  = (const float*)d_in[8];
    float* out = (float*)d_out;

    const int N  = in_sizes[0] / 128;     // 100000
    const int E  = in_sizes[1] / 2;       // 3200000
    const int ng = out_size / 10;         // 256

    const int NCHUNK = (N + 255) / 256;   // 391
    const int NB     = (N + 63) / 64;     // 1563 buckets

    // ---- workspace layout (words) ----
    int*   rowptr = (int*)d_ws;                     // 102400
    int*   cursor = rowptr + 102400;                // 102400 (cnt, then cursors)
    int*   chunk  = cursor + 102400;                // 2048
    int*   bcur   = chunk + 2048;                   // 2048
    float* dis    = (float*)(bcur + 2048);          // 102400
    int*   csr    = (int*)(dis + 102400);           // E
    // region A: tmp(int2,E = 2E words) -> Hb1(uint, N*64) -> agg2(float, N*64)
    int2*  tmp    = (int2*)(csr + E);
    u32*   Hb1    = (u32*)tmp;
    float* agg2   = (float*)tmp;
    size_t regA   = (size_t)2 * E > (size_t)N * 64 ? (size_t)2 * E : (size_t)N * 64;
    float* agg1   = (float*)((int*)tmp + regA);     // N*128
    u16*   Hb2    = (u16*)(agg1 + (size_t)N * 128); // N*64 ushorts (N*32 words)
    float* g      = (float*)((int*)Hb2 + (size_t)N * 32);  // ng*64

    // ---- CSR build (counting sort, bucketed placement) ----
    k_zero_int<<<(N + 255) / 256, 256, 0, stream>>>(cursor, N);
    k_count<<<(E + 255) / 256, 256, 0, stream>>>(ei, cursor, E, N);
    k_chunk_sum<<<NCHUNK, 256, 0, stream>>>(cursor, chunk, N);
    k_scan_chunks<<<1, 512, 0, stream>>>(chunk, chunk + 1024, NCHUNK);
    k_write_rowptr<<<NCHUNK, 256, 0, stream>>>(cursor, chunk + 1024, rowptr, cursor, N, E);
    k_bcur<<<(NB + 255) / 256, 256, 0, stream>>>(rowptr, bcur, NB);
    k_bucket<<<(E + 255) / 256, 256, 0, stream>>>(ei, bcur, tmp, E, N);
    k_place<<<(E + 255) / 256, 256, 0, stream>>>(tmp, cursor, csr, E);
    k_dis<<<(N + 255) / 256, 256, 0, stream>>>(rowptr, dis, N);

    // ---- layer 1 ----
    k_gemm<64, 128, 4, false><<<(N + 63) / 64, 256, 0, stream>>>(x, W1, dis, (uint4*)Hb1, N);
    k_agg1<<<(N + 3) / 4, 256, 0, stream>>>(rowptr, csr, dis, Hb1, b1, agg1, N);

    // ---- layer 2 ----
    k_gemm<64, 64, 2, true><<<(N + 63) / 64, 256, 0, stream>>>(agg1, W2, dis, (uint4*)Hb2, N);
    k_agg2<<<(N + 3) / 4, 256, 0, stream>>>(rowptr, csr, dis, Hb2, b2, agg2, N);

    // ---- pool + classifier ----
    k_pool<<<ng, 256, 0, stream>>>(batch, agg2, g, N);
    k_fc<<<1, 256, 0, stream>>>(g, Wfc, bfc, out, ng);
}

// Round 5
// 831.891 us; speedup vs baseline: 1.4526x; 1.4526x over previous
//
#include <hip/hip_runtime.h>
#include <math.h>

typedef unsigned int  u32;
typedef unsigned short u16;

__device__ inline u32 bf16_rne(float f) {
    u32 u = __float_as_uint(f);
    return (u + 0x7FFFu + ((u >> 16) & 1u)) >> 16;
}
__device__ inline float bf_lo(u32 u) { return __uint_as_float(u << 16); }
__device__ inline float bf_hi(u32 u) { return __uint_as_float(u & 0xFFFF0000u); }

// ================= CSR build =================

__global__ __launch_bounds__(256) void k_zero_int(int* p, int n) {
    int i = blockIdx.x * 256 + threadIdx.x;
    if (i < n) p[i] = 0;
}

// 4 independent edges/thread for atomic MLP
__global__ __launch_bounds__(256) void k_count4(const int* __restrict__ ei,
                                                int* __restrict__ cnt,
                                                int E, int N) {
    int t = blockIdx.x * 256 + threadIdx.x;
    int G = gridDim.x * 256;
#pragma unroll
    for (int j = 0; j < 4; ++j) {
        int i = t + j * G;
        if (i < E) {
            int d = ei[E + i];
            if ((unsigned)d < (unsigned)N) atomicAdd(&cnt[d], 1);
        }
    }
}

__global__ __launch_bounds__(256) void k_chunk_sum(const int* __restrict__ cnt,
                                                   int* __restrict__ chunkSum,
                                                   int N) {
    __shared__ int red[256];
    int t = threadIdx.x;
    int i = blockIdx.x * 256 + t;
    red[t] = (i < N) ? cnt[i] : 0;
    __syncthreads();
    for (int off = 128; off > 0; off >>= 1) {
        if (t < off) red[t] += red[t + off];
        __syncthreads();
    }
    if (t == 0) chunkSum[blockIdx.x] = red[0];
}

__global__ __launch_bounds__(512) void k_scan_chunks(const int* __restrict__ chunkSum,
                                                     int* __restrict__ chunkOff,
                                                     int nchunk) {
    __shared__ int sc[512];
    int t = threadIdx.x;
    int v = (t < nchunk) ? chunkSum[t] : 0;
    sc[t] = v;
    __syncthreads();
    for (int off = 1; off < 512; off <<= 1) {
        int u = (t >= off) ? sc[t - off] : 0;
        __syncthreads();
        sc[t] += u;
        __syncthreads();
    }
    if (t < nchunk) chunkOff[t] = sc[t] - v;
}

__global__ __launch_bounds__(256) void k_write_rowptr(const int* __restrict__ cnt,
                                                      const int* __restrict__ chunkOff,
                                                      int* __restrict__ rowptr,
                                                      int* __restrict__ cursor,
                                                      int N, int E) {
    __shared__ int sc[256];
    int t = threadIdx.x;
    int i = blockIdx.x * 256 + t;
    int v = (i < N) ? cnt[i] : 0;
    sc[t] = v;
    __syncthreads();
    for (int off = 1; off < 256; off <<= 1) {
        int u = (t >= off) ? sc[t - off] : 0;
        __syncthreads();
        sc[t] += u;
        __syncthreads();
    }
    if (i < N) {
        int ex = chunkOff[blockIdx.x] + sc[t] - v;
        rowptr[i] = ex;
        cursor[i] = ex;
        if (i == N - 1) rowptr[N] = ex + v;
    }
}

// direct placement: 100K cursors (low contention), 4 edges/thread so 4
// atomic->store chains overlap per lane
__global__ __launch_bounds__(256) void k_fill4(const int* __restrict__ ei,
                                               int* __restrict__ cursor,
                                               int* __restrict__ csr,
                                               int E, int N) {
    int t = blockIdx.x * 256 + threadIdx.x;
    int G = gridDim.x * 256;
    int i0 = t, i1 = t + G, i2 = t + 2 * G, i3 = t + 3 * G;
    int s0 = 0, s1 = 0, s2 = 0, s3 = 0, d0 = -1, d1 = -1, d2 = -1, d3 = -1;
    if (i0 < E) { s0 = ei[i0]; d0 = ei[E + i0]; }
    if (i1 < E) { s1 = ei[i1]; d1 = ei[E + i1]; }
    if (i2 < E) { s2 = ei[i2]; d2 = ei[E + i2]; }
    if (i3 < E) { s3 = ei[i3]; d3 = ei[E + i3]; }
    bool v0 = (unsigned)d0 < (unsigned)N, v1 = (unsigned)d1 < (unsigned)N;
    bool v2 = (unsigned)d2 < (unsigned)N, v3 = (unsigned)d3 < (unsigned)N;
    int p0 = v0 ? atomicAdd(&cursor[d0], 1) : 0;
    int p1 = v1 ? atomicAdd(&cursor[d1], 1) : 0;
    int p2 = v2 ? atomicAdd(&cursor[d2], 1) : 0;
    int p3 = v3 ? atomicAdd(&cursor[d3], 1) : 0;
    if (v0) csr[p0] = s0;
    if (v1) csr[p1] = s1;
    if (v2) csr[p2] = s2;
    if (v3) csr[p3] = s3;
}

__global__ __launch_bounds__(256) void k_dis(const int* __restrict__ rowptr,
                                             float* __restrict__ dis, int n) {
    int i = blockIdx.x * 256 + threadIdx.x;
    if (i < n) {
        float deg = (float)(rowptr[i + 1] - rowptr[i]) + 1.0f;
        dis[i] = rsqrtf(deg);
    }
}

// ========== GEMM: Hb = bf16( (X @ W) * dis[row] ), packed 2 cols/uint ==========

template <int BM, int BN, int TM, bool RELU_IN>
__global__ __launch_bounds__(256) void k_gemm(
    const float* __restrict__ X, const float* __restrict__ W,
    const float* __restrict__ dis, uint4* __restrict__ Hb, int M)
{
    constexpr int K = 128;
    constexpr int TN = 8;
    constexpr int RG = BM / TM;
    constexpr int LSTR = BM + 4;
    __shared__ float xs[K * LSTR];

    const int tid = threadIdx.x;
    const int m0 = blockIdx.x * BM;

    const float4* X4 = (const float4*)X;
    constexpr int NV = BM * (K / 4) / 256;
#pragma unroll
    for (int i = 0; i < NV; ++i) {
        int idx = tid + i * 256;
        int r = idx >> 5;
        int kq = idx & 31;
        float4 v = make_float4(0.f, 0.f, 0.f, 0.f);
        int gr = m0 + r;
        if (gr < M) v = X4[gr * 32 + kq];
        if (RELU_IN) {
            v.x = fmaxf(v.x, 0.f); v.y = fmaxf(v.y, 0.f);
            v.z = fmaxf(v.z, 0.f); v.w = fmaxf(v.w, 0.f);
        }
        int kb = kq * 4;
        xs[(kb + 0) * LSTR + r] = v.x;
        xs[(kb + 1) * LSTR + r] = v.y;
        xs[(kb + 2) * LSTR + r] = v.z;
        xs[(kb + 3) * LSTR + r] = v.w;
    }
    __syncthreads();

    const int rg = tid % RG;
    const int cg = tid / RG;

    float acc[TM][TN];
#pragma unroll
    for (int j = 0; j < TM; ++j)
#pragma unroll
        for (int c = 0; c < TN; ++c) acc[j][c] = 0.f;

    const float4* W4 = (const float4*)W;
#pragma unroll 4
    for (int k = 0; k < K; ++k) {
        float a[TM];
        if constexpr (TM == 4) {
            float4 av = *(const float4*)&xs[k * LSTR + rg * 4];
            a[0] = av.x; a[1] = av.y; a[2] = av.z; a[3] = av.w;
        } else {
            float2 av = *(const float2*)&xs[k * LSTR + rg * 2];
            a[0] = av.x; a[1] = av.y;
        }
        float4 b0 = W4[k * (BN / 4) + cg * 2];
        float4 b1 = W4[k * (BN / 4) + cg * 2 + 1];
#pragma unroll
        for (int j = 0; j < TM; ++j) {
            acc[j][0] = fmaf(a[j], b0.x, acc[j][0]);
            acc[j][1] = fmaf(a[j], b0.y, acc[j][1]);
            acc[j][2] = fmaf(a[j], b0.z, acc[j][2]);
            acc[j][3] = fmaf(a[j], b0.w, acc[j][3]);
            acc[j][4] = fmaf(a[j], b1.x, acc[j][4]);
            acc[j][5] = fmaf(a[j], b1.y, acc[j][5]);
            acc[j][6] = fmaf(a[j], b1.z, acc[j][6]);
            acc[j][7] = fmaf(a[j], b1.w, acc[j][7]);
        }
    }

#pragma unroll
    for (int j = 0; j < TM; ++j) {
        int r = m0 + rg * TM + j;
        if (r < M) {
            float dv = dis[r];
            uint4 p;
            p.x = bf16_rne(acc[j][0] * dv) | (bf16_rne(acc[j][1] * dv) << 16);
            p.y = bf16_rne(acc[j][2] * dv) | (bf16_rne(acc[j][3] * dv) << 16);
            p.z = bf16_rne(acc[j][4] * dv) | (bf16_rne(acc[j][5] * dv) << 16);
            p.w = bf16_rne(acc[j][6] * dv) | (bf16_rne(acc[j][7] * dv) << 16);
            Hb[r * (BN / 8) + cg] = p;
        }
    }
}

// ====== Aggregate L1 (D=128): AGG[n] = dn*(sum Hs[src] + Hs[n]) + bias ======

__global__ __launch_bounds__(256) void k_agg1(
    const int* __restrict__ rowptr, const int* __restrict__ csr,
    const float* __restrict__ dis, const u32* __restrict__ Hb,
    const float* __restrict__ bias, float* __restrict__ AGG, int N)
{
    int n = (blockIdx.x * 256 + threadIdx.x) >> 6;
    int lane = threadIdx.x & 63;
    if (n >= N) return;
    int e = rowptr[n];
    const int s1 = rowptr[n + 1];
    const float dn = dis[n];

    float a0 = 0.f, a1 = 0.f, b0 = 0.f, b1 = 0.f;
    float c0 = 0.f, c1 = 0.f, d0 = 0.f, d1 = 0.f;

    for (; e + 8 <= s1; e += 8) {
        int i0 = csr[e + 0], i1 = csr[e + 1], i2 = csr[e + 2], i3 = csr[e + 3];
        int i4 = csr[e + 4], i5 = csr[e + 5], i6 = csr[e + 6], i7 = csr[e + 7];
        u32 u0 = Hb[i0 * 64 + lane], u1 = Hb[i1 * 64 + lane];
        u32 u2 = Hb[i2 * 64 + lane], u3 = Hb[i3 * 64 + lane];
        u32 u4 = Hb[i4 * 64 + lane], u5 = Hb[i5 * 64 + lane];
        u32 u6 = Hb[i6 * 64 + lane], u7 = Hb[i7 * 64 + lane];
        a0 += bf_lo(u0) + bf_lo(u4); a1 += bf_hi(u0) + bf_hi(u4);
        b0 += bf_lo(u1) + bf_lo(u5); b1 += bf_hi(u1) + bf_hi(u5);
        c0 += bf_lo(u2) + bf_lo(u6); c1 += bf_hi(u2) + bf_hi(u6);
        d0 += bf_lo(u3) + bf_lo(u7); d1 += bf_hi(u3) + bf_hi(u7);
    }
    for (; e < s1; ++e) {
        u32 u = Hb[csr[e] * 64 + lane];
        a0 += bf_lo(u); a1 += bf_hi(u);
    }

    u32 self = Hb[n * 64 + lane];
    float2 bv = ((const float2*)bias)[lane];
    float2 o;
    o.x = fmaf(dn, (a0 + b0) + (c0 + d0) + bf_lo(self), bv.x);
    o.y = fmaf(dn, (a1 + b1) + (c1 + d1) + bf_hi(self), bv.y);
    ((float2*)AGG)[n * 64 + lane] = o;
}

// ====== Aggregate L2 (D=64) ======

__global__ __launch_bounds__(256) void k_agg2(
    const int* __restrict__ rowptr, const int* __restrict__ csr,
    const float* __restrict__ dis, const u16* __restrict__ Hb,
    const float* __restrict__ bias, float* __restrict__ AGG, int N)
{
    int n = (blockIdx.x * 256 + threadIdx.x) >> 6;
    int lane = threadIdx.x & 63;
    if (n >= N) return;
    int e = rowptr[n];
    const int s1 = rowptr[n + 1];
    const float dn = dis[n];

    float a0 = 0.f, b0 = 0.f, c0 = 0.f, d0 = 0.f;

    for (; e + 8 <= s1; e += 8) {
        int i0 = csr[e + 0], i1 = csr[e + 1], i2 = csr[e + 2], i3 = csr[e + 3];
        int i4 = csr[e + 4], i5 = csr[e + 5], i6 = csr[e + 6], i7 = csr[e + 7];
        float v0 = __uint_as_float((u32)Hb[i0 * 64 + lane] << 16);
        float v1 = __uint_as_float((u32)Hb[i1 * 64 + lane] << 16);
        float v2 = __uint_as_float((u32)Hb[i2 * 64 + lane] << 16);
        float v3 = __uint_as_float((u32)Hb[i3 * 64 + lane] << 16);
        float v4 = __uint_as_float((u32)Hb[i4 * 64 + lane] << 16);
        float v5 = __uint_as_float((u32)Hb[i5 * 64 + lane] << 16);
        float v6 = __uint_as_float((u32)Hb[i6 * 64 + lane] << 16);
        float v7 = __uint_as_float((u32)Hb[i7 * 64 + lane] << 16);
        a0 += v0 + v4; b0 += v1 + v5; c0 += v2 + v6; d0 += v3 + v7;
    }
    for (; e < s1; ++e)
        a0 += __uint_as_float((u32)Hb[csr[e] * 64 + lane] << 16);

    float self = __uint_as_float((u32)Hb[n * 64 + lane] << 16);
    AGG[n * 64 + lane] = fmaf(dn, (a0 + b0) + (c0 + d0) + self, bias[lane]);
}

// ================= mean pool over sorted batch =================

__device__ inline int lower_bound(const int* __restrict__ b, int n, int v) {
    int lo = 0, hi = n;
    while (lo < hi) { int m = (lo + hi) >> 1; if (b[m] < v) lo = m + 1; else hi = m; }
    return lo;
}

__global__ __launch_bounds__(256) void k_pool(
    const int* __restrict__ batch, const float* __restrict__ AGG2,
    float* __restrict__ G, int n)
{
    int g = blockIdx.x;
    int start = lower_bound(batch, n, g);
    int end   = lower_bound(batch, n, g + 1);
    int tid = threadIdx.x;
    int f = tid & 63, stripe = tid >> 6;
    float acc = 0.f;
    for (int i = start + stripe; i < end; i += 4)
        acc += AGG2[(size_t)i * 64 + f];
    __shared__ float red[256];
    red[tid] = acc;
    __syncthreads();
    if (tid < 64) {
        float s = red[tid] + red[tid + 64] + red[tid + 128] + red[tid + 192];
        float c = (float)(end - start);
        G[g * 64 + tid] = s / fmaxf(c, 1.0f);
    }
}

// ================= classifier =================

__global__ __launch_bounds__(256) void k_fc(
    const float* __restrict__ G, const float* __restrict__ Wfc,
    const float* __restrict__ bfc, float* __restrict__ out, int ng)
{
    __shared__ float wl[640];
    __shared__ float bl[10];
    int tid = threadIdx.x;
    for (int i = tid; i < 640; i += 256) wl[i] = Wfc[i];
    if (tid < 10) bl[tid] = bfc[tid];
    __syncthreads();
    if (tid >= ng) return;
    float acc[10];
#pragma unroll
    for (int c = 0; c < 10; ++c) acc[c] = bl[c];
    for (int k = 0; k < 64; ++k) {
        float gv = G[tid * 64 + k];
#pragma unroll
        for (int c = 0; c < 10; ++c) acc[c] = fmaf(gv, wl[k * 10 + c], acc[c]);
    }
#pragma unroll
    for (int c = 0; c < 10; ++c) out[tid * 10 + c] = acc[c];
}

// ================= launch =================

extern "C" void kernel_launch(void* const* d_in, const int* in_sizes, int n_in,
                              void* d_out, int out_size, void* d_ws, size_t ws_size,
                              hipStream_t stream)
{
    const float* x    = (const float*)d_in[0];
    const int*   ei   = (const int*)d_in[1];
    const int*   batch= (const int*)d_in[2];
    const float* W1   = (const float*)d_in[3];
    const float* b1   = (const float*)d_in[4];
    const float* W2   = (const float*)d_in[5];
    const float* b2   = (const float*)d_in[6];
    const float* Wfc  = (const float*)d_in[7];
    const float* bfc  = (const float*)d_in[8];
    float* out = (float*)d_out;

    const int N  = in_sizes[0] / 128;     // 100000
    const int E  = in_sizes[1] / 2;       // 3200000
    const int ng = out_size / 10;         // 256

    const int NCHUNK = (N + 255) / 256;   // 391

    // ---- workspace layout (words) ----
    int*   rowptr = (int*)d_ws;                     // 102400
    int*   cursor = rowptr + 102400;                // 102400 (cnt, then cursors)
    int*   chunk  = cursor + 102400;                // 2048
    float* dis    = (float*)(chunk + 2048);         // 102400
    int*   csr    = (int*)(dis + 102400);           // E
    // region A: Hb1(uint, N*64) then reused as agg2(float, N*64)
    u32*   Hb1    = (u32*)(csr + E);
    float* agg2   = (float*)Hb1;
    float* agg1   = (float*)((int*)Hb1 + (size_t)N * 64);   // N*128
    u16*   Hb2    = (u16*)(agg1 + (size_t)N * 128);         // N*64 u16 (N*32 words)
    float* g      = (float*)((int*)Hb2 + (size_t)N * 32);   // ng*64

    // ---- CSR build (counting sort, direct placement) ----
    k_zero_int<<<(N + 255) / 256, 256, 0, stream>>>(cursor, N);
    k_count4<<<(E / 4 + 255) / 256, 256, 0, stream>>>(ei, cursor, E, N);
    k_chunk_sum<<<NCHUNK, 256, 0, stream>>>(cursor, chunk, N);
    k_scan_chunks<<<1, 512, 0, stream>>>(chunk, chunk + 1024, NCHUNK);
    k_write_rowptr<<<NCHUNK, 256, 0, stream>>>(cursor, chunk + 1024, rowptr, cursor, N, E);
    k_fill4<<<(E / 4 + 255) / 256, 256, 0, stream>>>(ei, cursor, csr, E, N);
    k_dis<<<(N + 255) / 256, 256, 0, stream>>>(rowptr, dis, N);

    // ---- layer 1 ----
    k_gemm<64, 128, 4, false><<<(N + 63) / 64, 256, 0, stream>>>(x, W1, dis, (uint4*)Hb1, N);
    k_agg1<<<(N + 3) / 4, 256, 0, stream>>>(rowptr, csr, dis, Hb1, b1, agg1, N);

    // ---- layer 2 ----
    k_gemm<64, 64, 2, true><<<(N + 63) / 64, 256, 0, stream>>>(agg1, W2, dis, (uint4*)Hb2, N);
    k_agg2<<<(N + 3) / 4, 256, 0, stream>>>(rowptr, csr, dis, Hb2, b2, agg2, N);

    // ---- pool + classifier ----
    k_pool<<<ng, 256, 0, stream>>>(batch, agg2, g, N);
    k_fc<<<1, 256, 0, stream>>>(g, Wfc, bfc, out, ng);
}

// Round 6
// 599.102 us; speedup vs baseline: 2.0170x; 1.3886x over previous
//
#include <hip/hip_runtime.h>
#include <math.h>

typedef unsigned int  u32;
typedef unsigned short u16;

#define TILE1 2048      // edges per pass-1 block
#define BKW   1024      // nodes per bucket (shift 10)
#define CAP   36864     // tmp slots per bucket (mean 32768, +22 sigma)

__device__ inline u32 bf16_rne(float f) {
    u32 u = __float_as_uint(f);
    return (u + 0x7FFFu + ((u >> 16) & 1u)) >> 16;
}
__device__ inline float bf_lo(u32 u) { return __uint_as_float(u << 16); }
__device__ inline float bf_hi(u32 u) { return __uint_as_float(u & 0xFFFF0000u); }

// ================= CSR build: 2-pass radix partition =================

__global__ __launch_bounds__(128) void k_zero_small(int* p, int n) {
    if (threadIdx.x < n) p[threadIdx.x] = 0;
}

// pass 1: partition edges into buckets of 1024 dst nodes.
// packed value = (dstLocal<<17) | src   (src < 2^17, dstLocal < 1024)
__global__ __launch_bounds__(256) void k_part1(const int* __restrict__ ei,
                                               int* __restrict__ bucketCur,
                                               u32* __restrict__ tmp,
                                               int E, int N, int NBK) {
    __shared__ int hist[128];
    __shared__ int base[128];
    const int tid = threadIdx.x;
    if (tid < NBK) hist[tid] = 0;
    __syncthreads();

    const int t0 = blockIdx.x * TILE1;
    int sv[8], dv[8], key[8];
#pragma unroll
    for (int j = 0; j < 8; ++j) {
        int i = t0 + j * 256 + tid;
        key[j] = -1;
        if (i < E) {
            sv[j] = ei[i];
            dv[j] = ei[E + i];
            if ((unsigned)dv[j] < (unsigned)N && (unsigned)sv[j] < (unsigned)N) {
                key[j] = dv[j] >> 10;
                atomicAdd(&hist[key[j]], 1);
            }
        }
    }
    __syncthreads();
    if (tid < NBK) {
        base[tid] = atomicAdd(&bucketCur[tid], hist[tid]);
        hist[tid] = 0;                 // reuse as running cursor
    }
    __syncthreads();
#pragma unroll
    for (int j = 0; j < 8; ++j) {
        if (key[j] >= 0) {
            int slot = atomicAdd(&hist[key[j]], 1);
            int off = base[key[j]] + slot;
            if (off < CAP)
                tmp[(size_t)key[j] * CAP + off] =
                    ((u32)(dv[j] & 1023) << 17) | (u32)sv[j];
        }
    }
}

// exclusive scan of bucket counts (NBK <= 128); also rowptr[N] = total
__global__ __launch_bounds__(128) void k_scan_bk(const int* __restrict__ cnt,
                                                 int* __restrict__ start,
                                                 int* __restrict__ rowptr,
                                                 int NBK, int N) {
    __shared__ int sc[128];
    int t = threadIdx.x;
    int v = (t < NBK) ? cnt[t] : 0;
    sc[t] = v;
    __syncthreads();
    for (int off = 1; off < 128; off <<= 1) {
        int u = (t >= off) ? sc[t - off] : 0;
        __syncthreads();
        sc[t] += u;
        __syncthreads();
    }
    if (t < NBK) start[t] = sc[t] - v;     // exclusive
    if (t == NBK - 1) {
        start[NBK] = sc[t];
        rowptr[N] = sc[t];
    }
}

// pass 2: one block per bucket. histogram -> rowptr + dis, then place csr.
__global__ __launch_bounds__(256) void k_part2(const int* __restrict__ bucketCnt,
                                               const int* __restrict__ bucketStart,
                                               const u32* __restrict__ tmp,
                                               int* __restrict__ csr,
                                               int* __restrict__ rowptr,
                                               float* __restrict__ dis, int N) {
    __shared__ int hist[1024];
    __shared__ int ts[256];
    const int b = blockIdx.x;
    const int t = threadIdx.x;
    const int cnt = bucketCnt[b];
    const int start = bucketStart[b];
    const u32* src = tmp + (size_t)b * CAP;

    for (int i = t; i < 1024; i += 256) hist[i] = 0;
    __syncthreads();
    for (int i = t; i < cnt; i += 256)
        atomicAdd(&hist[src[i] >> 17], 1);
    __syncthreads();

    // exclusive scan of hist[0..1023]
    int h0 = hist[t * 4], h1 = hist[t * 4 + 1], h2 = hist[t * 4 + 2], h3 = hist[t * 4 + 3];
    int s = h0 + h1 + h2 + h3;
    ts[t] = s;
    __syncthreads();
    for (int off = 1; off < 256; off <<= 1) {
        int u = (t >= off) ? ts[t - off] : 0;
        __syncthreads();
        ts[t] += u;
        __syncthreads();
    }
    int ex = ts[t] - s;
    hist[t * 4]     = ex;
    hist[t * 4 + 1] = ex + h0;
    hist[t * 4 + 2] = ex + h0 + h1;
    hist[t * 4 + 3] = ex + h0 + h1 + h2;
    __syncthreads();

    // rowptr + dis for this bucket's nodes
    const int nbase = b << 10;
    for (int l = t; l < 1024; l += 256) {
        int gn = nbase + l;
        if (gn < N) {
            int e0 = hist[l];
            int e1 = (l < 1023) ? hist[l + 1] : cnt;
            rowptr[gn] = start + e0;
            dis[gn] = rsqrtf((float)(e1 - e0) + 1.0f);
        }
    }
    __syncthreads();

    // place (hist becomes running cursor)
    for (int i = t; i < cnt; i += 256) {
        u32 v = src[i];
        int p = atomicAdd(&hist[v >> 17], 1);
        csr[start + p] = (int)(v & 0x1FFFFu);
    }
}

// ========== GEMM: Hb = bf16( (X @ W) * dis[row] ), packed 2 cols/uint ==========

template <int BM, int BN, int TM, bool RELU_IN>
__global__ __launch_bounds__(256) void k_gemm(
    const float* __restrict__ X, const float* __restrict__ W,
    const float* __restrict__ dis, uint4* __restrict__ Hb, int M)
{
    constexpr int K = 128;
    constexpr int TN = 8;
    constexpr int RG = BM / TM;
    constexpr int LSTR = BM + 4;
    __shared__ float xs[K * LSTR];

    const int tid = threadIdx.x;
    const int m0 = blockIdx.x * BM;

    const float4* X4 = (const float4*)X;
    constexpr int NV = BM * (K / 4) / 256;
#pragma unroll
    for (int i = 0; i < NV; ++i) {
        int idx = tid + i * 256;
        int r = idx >> 5;
        int kq = idx & 31;
        float4 v = make_float4(0.f, 0.f, 0.f, 0.f);
        int gr = m0 + r;
        if (gr < M) v = X4[gr * 32 + kq];
        if (RELU_IN) {
            v.x = fmaxf(v.x, 0.f); v.y = fmaxf(v.y, 0.f);
            v.z = fmaxf(v.z, 0.f); v.w = fmaxf(v.w, 0.f);
        }
        int kb = kq * 4;
        xs[(kb + 0) * LSTR + r] = v.x;
        xs[(kb + 1) * LSTR + r] = v.y;
        xs[(kb + 2) * LSTR + r] = v.z;
        xs[(kb + 3) * LSTR + r] = v.w;
    }
    __syncthreads();

    const int rg = tid % RG;
    const int cg = tid / RG;

    float acc[TM][TN];
#pragma unroll
    for (int j = 0; j < TM; ++j)
#pragma unroll
        for (int c = 0; c < TN; ++c) acc[j][c] = 0.f;

    const float4* W4 = (const float4*)W;
#pragma unroll 4
    for (int k = 0; k < K; ++k) {
        float a[TM];
        if constexpr (TM == 4) {
            float4 av = *(const float4*)&xs[k * LSTR + rg * 4];
            a[0] = av.x; a[1] = av.y; a[2] = av.z; a[3] = av.w;
        } else {
            float2 av = *(const float2*)&xs[k * LSTR + rg * 2];
            a[0] = av.x; a[1] = av.y;
        }
        float4 b0 = W4[k * (BN / 4) + cg * 2];
        float4 b1 = W4[k * (BN / 4) + cg * 2 + 1];
#pragma unroll
        for (int j = 0; j < TM; ++j) {
            acc[j][0] = fmaf(a[j], b0.x, acc[j][0]);
            acc[j][1] = fmaf(a[j], b0.y, acc[j][1]);
            acc[j][2] = fmaf(a[j], b0.z, acc[j][2]);
            acc[j][3] = fmaf(a[j], b0.w, acc[j][3]);
            acc[j][4] = fmaf(a[j], b1.x, acc[j][4]);
            acc[j][5] = fmaf(a[j], b1.y, acc[j][5]);
            acc[j][6] = fmaf(a[j], b1.z, acc[j][6]);
            acc[j][7] = fmaf(a[j], b1.w, acc[j][7]);
        }
    }

#pragma unroll
    for (int j = 0; j < TM; ++j) {
        int r = m0 + rg * TM + j;
        if (r < M) {
            float dv = dis[r];
            uint4 p;
            p.x = bf16_rne(acc[j][0] * dv) | (bf16_rne(acc[j][1] * dv) << 16);
            p.y = bf16_rne(acc[j][2] * dv) | (bf16_rne(acc[j][3] * dv) << 16);
            p.z = bf16_rne(acc[j][4] * dv) | (bf16_rne(acc[j][5] * dv) << 16);
            p.w = bf16_rne(acc[j][6] * dv) | (bf16_rne(acc[j][7] * dv) << 16);
            Hb[r * (BN / 8) + cg] = p;
        }
    }
}

// ====== Aggregate L1 (D=128): AGG[n] = dn*(sum Hs[src] + Hs[n]) + bias ======

__global__ __launch_bounds__(256) void k_agg1(
    const int* __restrict__ rowptr, const int* __restrict__ csr,
    const float* __restrict__ dis, const u32* __restrict__ Hb,
    const float* __restrict__ bias, float* __restrict__ AGG, int N)
{
    int n = (blockIdx.x * 256 + threadIdx.x) >> 6;
    int lane = threadIdx.x & 63;
    if (n >= N) return;
    int e = rowptr[n];
    const int s1 = rowptr[n + 1];
    const float dn = dis[n];

    float a0 = 0.f, a1 = 0.f, b0 = 0.f, b1 = 0.f;
    float c0 = 0.f, c1 = 0.f, d0 = 0.f, d1 = 0.f;

    for (; e + 8 <= s1; e += 8) {
        int i0 = csr[e + 0], i1 = csr[e + 1], i2 = csr[e + 2], i3 = csr[e + 3];
        int i4 = csr[e + 4], i5 = csr[e + 5], i6 = csr[e + 6], i7 = csr[e + 7];
        u32 u0 = Hb[i0 * 64 + lane], u1 = Hb[i1 * 64 + lane];
        u32 u2 = Hb[i2 * 64 + lane], u3 = Hb[i3 * 64 + lane];
        u32 u4 = Hb[i4 * 64 + lane], u5 = Hb[i5 * 64 + lane];
        u32 u6 = Hb[i6 * 64 + lane], u7 = Hb[i7 * 64 + lane];
        a0 += bf_lo(u0) + bf_lo(u4); a1 += bf_hi(u0) + bf_hi(u4);
        b0 += bf_lo(u1) + bf_lo(u5); b1 += bf_hi(u1) + bf_hi(u5);
        c0 += bf_lo(u2) + bf_lo(u6); c1 += bf_hi(u2) + bf_hi(u6);
        d0 += bf_lo(u3) + bf_lo(u7); d1 += bf_hi(u3) + bf_hi(u7);
    }
    for (; e < s1; ++e) {
        u32 u = Hb[csr[e] * 64 + lane];
        a0 += bf_lo(u); a1 += bf_hi(u);
    }

    u32 self = Hb[n * 64 + lane];
    float2 bv = ((const float2*)bias)[lane];
    float2 o;
    o.x = fmaf(dn, (a0 + b0) + (c0 + d0) + bf_lo(self), bv.x);
    o.y = fmaf(dn, (a1 + b1) + (c1 + d1) + bf_hi(self), bv.y);
    ((float2*)AGG)[n * 64 + lane] = o;
}

// ====== Aggregate L2 (D=64) ======

__global__ __launch_bounds__(256) void k_agg2(
    const int* __restrict__ rowptr, const int* __restrict__ csr,
    const float* __restrict__ dis, const u16* __restrict__ Hb,
    const float* __restrict__ bias, float* __restrict__ AGG, int N)
{
    int n = (blockIdx.x * 256 + threadIdx.x) >> 6;
    int lane = threadIdx.x & 63;
    if (n >= N) return;
    int e = rowptr[n];
    const int s1 = rowptr[n + 1];
    const float dn = dis[n];

    float a0 = 0.f, b0 = 0.f, c0 = 0.f, d0 = 0.f;

    for (; e + 8 <= s1; e += 8) {
        int i0 = csr[e + 0], i1 = csr[e + 1], i2 = csr[e + 2], i3 = csr[e + 3];
        int i4 = csr[e + 4], i5 = csr[e + 5], i6 = csr[e + 6], i7 = csr[e + 7];
        float v0 = __uint_as_float((u32)Hb[i0 * 64 + lane] << 16);
        float v1 = __uint_as_float((u32)Hb[i1 * 64 + lane] << 16);
        float v2 = __uint_as_float((u32)Hb[i2 * 64 + lane] << 16);
        float v3 = __uint_as_float((u32)Hb[i3 * 64 + lane] << 16);
        float v4 = __uint_as_float((u32)Hb[i4 * 64 + lane] << 16);
        float v5 = __uint_as_float((u32)Hb[i5 * 64 + lane] << 16);
        float v6 = __uint_as_float((u32)Hb[i6 * 64 + lane] << 16);
        float v7 = __uint_as_float((u32)Hb[i7 * 64 + lane] << 16);
        a0 += v0 + v4; b0 += v1 + v5; c0 += v2 + v6; d0 += v3 + v7;
    }
    for (; e < s1; ++e)
        a0 += __uint_as_float((u32)Hb[csr[e] * 64 + lane] << 16);

    float self = __uint_as_float((u32)Hb[n * 64 + lane] << 16);
    AGG[n * 64 + lane] = fmaf(dn, (a0 + b0) + (c0 + d0) + self, bias[lane]);
}

// ================= mean pool over sorted batch =================

__device__ inline int lower_bound(const int* __restrict__ b, int n, int v) {
    int lo = 0, hi = n;
    while (lo < hi) { int m = (lo + hi) >> 1; if (b[m] < v) lo = m + 1; else hi = m; }
    return lo;
}

__global__ __launch_bounds__(256) void k_pool(
    const int* __restrict__ batch, const float* __restrict__ AGG2,
    float* __restrict__ G, int n)
{
    int g = blockIdx.x;
    int start = lower_bound(batch, n, g);
    int end   = lower_bound(batch, n, g + 1);
    int tid = threadIdx.x;
    int f = tid & 63, stripe = tid >> 6;
    float acc = 0.f;
    for (int i = start + stripe; i < end; i += 4)
        acc += AGG2[(size_t)i * 64 + f];
    __shared__ float red[256];
    red[tid] = acc;
    __syncthreads();
    if (tid < 64) {
        float s = red[tid] + red[tid + 64] + red[tid + 128] + red[tid + 192];
        float c = (float)(end - start);
        G[g * 64 + tid] = s / fmaxf(c, 1.0f);
    }
}

// ================= classifier =================

__global__ __launch_bounds__(256) void k_fc(
    const float* __restrict__ G, const float* __restrict__ Wfc,
    const float* __restrict__ bfc, float* __restrict__ out, int ng)
{
    __shared__ float wl[640];
    __shared__ float bl[10];
    int tid = threadIdx.x;
    for (int i = tid; i < 640; i += 256) wl[i] = Wfc[i];
    if (tid < 10) bl[tid] = bfc[tid];
    __syncthreads();
    if (tid >= ng) return;
    float acc[10];
#pragma unroll
    for (int c = 0; c < 10; ++c) acc[c] = bl[c];
    for (int k = 0; k < 64; ++k) {
        float gv = G[tid * 64 + k];
#pragma unroll
        for (int c = 0; c < 10; ++c) acc[c] = fmaf(gv, wl[k * 10 + c], acc[c]);
    }
#pragma unroll
    for (int c = 0; c < 10; ++c) out[tid * 10 + c] = acc[c];
}

// ================= launch =================

extern "C" void kernel_launch(void* const* d_in, const int* in_sizes, int n_in,
                              void* d_out, int out_size, void* d_ws, size_t ws_size,
                              hipStream_t stream)
{
    const float* x    = (const float*)d_in[0];
    const int*   ei   = (const int*)d_in[1];
    const int*   batch= (const int*)d_in[2];
    const float* W1   = (const float*)d_in[3];
    const float* b1   = (const float*)d_in[4];
    const float* W2   = (const float*)d_in[5];
    const float* b2   = (const float*)d_in[6];
    const float* Wfc  = (const float*)d_in[7];
    const float* bfc  = (const float*)d_in[8];
    float* out = (float*)d_out;

    const int N  = in_sizes[0] / 128;     // 100000
    const int E  = in_sizes[1] / 2;       // 3200000
    const int ng = out_size / 10;         // 256

    const int NBK = (N + BKW - 1) / BKW;  // 98 buckets

    // ---- workspace layout (words) ----
    int*   rowptr    = (int*)d_ws;                          // 102400 (N+1)
    int*   bucketCur = rowptr + 102400;                     // 256
    int*   bucketSt  = bucketCur + 256;                     // 256
    float* dis       = (float*)(bucketSt + 256);            // 102400
    int*   csr       = (int*)(dis + 102400);                // E
    // region A (6.4M words): tmp (NBK*CAP=3.62M) -> Hb1 (N*64) -> agg2 (N*64)
    u32*   tmp       = (u32*)(csr + E);
    u32*   Hb1       = tmp;
    float* agg2      = (float*)tmp;
    float* agg1      = (float*)((int*)tmp + (size_t)N * 64);    // N*128
    u16*   Hb2       = (u16*)(agg1 + (size_t)N * 128);          // N*64 u16
    float* g         = (float*)((int*)Hb2 + (size_t)N * 32);    // ng*64

    // ---- CSR build: radix partition ----
    k_zero_small<<<1, 128, 0, stream>>>(bucketCur, NBK);
    k_part1<<<(E + TILE1 - 1) / TILE1, 256, 0, stream>>>(ei, bucketCur, tmp, E, N, NBK);
    k_scan_bk<<<1, 128, 0, stream>>>(bucketCur, bucketSt, rowptr, NBK, N);
    k_part2<<<NBK, 256, 0, stream>>>(bucketCur, bucketSt, tmp, csr, rowptr, dis, N);

    // ---- layer 1 ----
    k_gemm<64, 128, 4, false><<<(N + 63) / 64, 256, 0, stream>>>(x, W1, dis, (uint4*)Hb1, N);
    k_agg1<<<(N + 3) / 4, 256, 0, stream>>>(rowptr, csr, dis, Hb1, b1, agg1, N);

    // ---- layer 2 ----
    k_gemm<64, 64, 2, true><<<(N + 63) / 64, 256, 0, stream>>>(agg1, W2, dis, (uint4*)Hb2, N);
    k_agg2<<<(N + 3) / 4, 256, 0, stream>>>(rowptr, csr, dis, Hb2, b2, agg2, N);

    // ---- pool + classifier ----
    k_pool<<<ng, 256, 0, stream>>>(batch, agg2, g, N);
    k_fc<<<1, 256, 0, stream>>>(g, Wfc, bfc, out, ng);
}

// Round 7
// 581.407 us; speedup vs baseline: 2.0784x; 1.0304x over previous
//
#include <hip/hip_runtime.h>
#include <math.h>

typedef unsigned int  u32;
typedef unsigned short u16;

#define TILE1 4096      // edges per pass-1 block (16/thread)
#define BKW   1024      // nodes per bucket (shift 10)
#define CAP   36864     // tmp slots per bucket (mean 32653, +22 sigma)

__device__ inline u32 bf16_rne(float f) {
    u32 u = __float_as_uint(f);
    return (u + 0x7FFFu + ((u >> 16) & 1u)) >> 16;
}
__device__ inline float bf_lo(u32 u) { return __uint_as_float(u << 16); }
__device__ inline float bf_hi(u32 u) { return __uint_as_float(u & 0xFFFF0000u); }

// ================= CSR build: 2-pass radix partition =================

__global__ __launch_bounds__(128) void k_zero_small(int* p, int n) {
    if (threadIdx.x < n) p[threadIdx.x] = 0;
}

// pass 1: partition edges into buckets of 1024 dst nodes.
// packed value = (dstLocal<<17) | src   (src < 2^17, dstLocal < 1024)
__global__ __launch_bounds__(256) void k_part1(const int* __restrict__ ei,
                                               int* __restrict__ bucketCur,
                                               u32* __restrict__ tmp,
                                               int E, int N, int NBK) {
    __shared__ int hist[128];
    __shared__ int base[128];
    const int tid = threadIdx.x;
    if (tid < NBK) hist[tid] = 0;
    __syncthreads();

    const int t0 = blockIdx.x * TILE1;
    int sv[16], dv[16], key[16];
#pragma unroll
    for (int j = 0; j < 16; ++j) {
        int i = t0 + j * 256 + tid;
        key[j] = -1;
        if (i < E) {
            sv[j] = ei[i];
            dv[j] = ei[E + i];
            if ((unsigned)dv[j] < (unsigned)N && (unsigned)sv[j] < (unsigned)N) {
                key[j] = dv[j] >> 10;
                atomicAdd(&hist[key[j]], 1);
            }
        }
    }
    __syncthreads();
    if (tid < NBK) {
        base[tid] = atomicAdd(&bucketCur[tid], hist[tid]);
        hist[tid] = 0;                 // reuse as running cursor
    }
    __syncthreads();
#pragma unroll
    for (int j = 0; j < 16; ++j) {
        if (key[j] >= 0) {
            int slot = atomicAdd(&hist[key[j]], 1);
            int off = base[key[j]] + slot;
            if (off < CAP)
                tmp[(size_t)key[j] * CAP + off] =
                    ((u32)(dv[j] & 1023) << 17) | (u32)sv[j];
        }
    }
}

// pass 2: one block per bucket. scan bucket counts (inline), histogram ->
// rowptr + dis, then place csr with LDS cursors.
__global__ __launch_bounds__(256) void k_part2(const int* __restrict__ bucketCnt,
                                               const u32* __restrict__ tmp,
                                               int* __restrict__ csr,
                                               int* __restrict__ rowptr,
                                               float* __restrict__ dis,
                                               int N, int NBK) {
    __shared__ int hist[1024];
    __shared__ int ts[256];
    __shared__ int sStart;
    const int b = blockIdx.x;
    const int t = threadIdx.x;

    // inline exclusive scan of bucketCnt to get this bucket's start
    int myCnt = (t < NBK) ? bucketCnt[t] : 0;
    ts[t] = myCnt;
    __syncthreads();
    for (int off = 1; off < 256; off <<= 1) {
        int u = (t >= off) ? ts[t - off] : 0;
        __syncthreads();
        ts[t] += u;
        __syncthreads();
    }
    if (t == b) sStart = ts[t] - myCnt;
    if (b == 0 && t == NBK - 1) rowptr[N] = ts[t];
    __syncthreads();
    const int start = sStart;
    const int cnt = bucketCnt[b];
    const u32* src = tmp + (size_t)b * CAP;

    for (int i = t; i < 1024; i += 256) hist[i] = 0;
    __syncthreads();
    for (int i = t; i < cnt; i += 256)
        atomicAdd(&hist[src[i] >> 17], 1);
    __syncthreads();

    // exclusive scan of hist[0..1023]
    int h0 = hist[t * 4], h1 = hist[t * 4 + 1], h2 = hist[t * 4 + 2], h3 = hist[t * 4 + 3];
    int s = h0 + h1 + h2 + h3;
    ts[t] = s;
    __syncthreads();
    for (int off = 1; off < 256; off <<= 1) {
        int u = (t >= off) ? ts[t - off] : 0;
        __syncthreads();
        ts[t] += u;
        __syncthreads();
    }
    int ex = ts[t] - s;
    hist[t * 4]     = ex;
    hist[t * 4 + 1] = ex + h0;
    hist[t * 4 + 2] = ex + h0 + h1;
    hist[t * 4 + 3] = ex + h0 + h1 + h2;
    __syncthreads();

    // rowptr + dis for this bucket's nodes
    const int nbase = b << 10;
    for (int l = t; l < 1024; l += 256) {
        int gn = nbase + l;
        if (gn < N) {
            int e0 = hist[l];
            int e1 = (l < 1023) ? hist[l + 1] : cnt;
            rowptr[gn] = start + e0;
            dis[gn] = rsqrtf((float)(e1 - e0) + 1.0f);
        }
    }
    __syncthreads();

    // place (hist becomes running cursor)
    for (int i = t; i < cnt; i += 256) {
        u32 v = src[i];
        int p = atomicAdd(&hist[v >> 17], 1);
        csr[start + p] = (int)(v & 0x1FFFFu);
    }
}

// ========== GEMM: Hb = bf16( (X @ W) * dis[row] ), packed 2 cols/uint ==========

template <int BM, int BN, int TM, bool RELU_IN>
__global__ __launch_bounds__(256) void k_gemm(
    const float* __restrict__ X, const float* __restrict__ W,
    const float* __restrict__ dis, uint4* __restrict__ Hb, int M)
{
    constexpr int K = 128;
    constexpr int TN = 8;
    constexpr int RG = BM / TM;
    constexpr int LSTR = BM + 4;
    __shared__ float xs[K * LSTR];

    const int tid = threadIdx.x;
    const int m0 = blockIdx.x * BM;

    const float4* X4 = (const float4*)X;
    constexpr int NV = BM * (K / 4) / 256;
#pragma unroll
    for (int i = 0; i < NV; ++i) {
        int idx = tid + i * 256;
        int r = idx >> 5;
        int kq = idx & 31;
        float4 v = make_float4(0.f, 0.f, 0.f, 0.f);
        int gr = m0 + r;
        if (gr < M) v = X4[gr * 32 + kq];
        if (RELU_IN) {
            v.x = fmaxf(v.x, 0.f); v.y = fmaxf(v.y, 0.f);
            v.z = fmaxf(v.z, 0.f); v.w = fmaxf(v.w, 0.f);
        }
        int kb = kq * 4;
        xs[(kb + 0) * LSTR + r] = v.x;
        xs[(kb + 1) * LSTR + r] = v.y;
        xs[(kb + 2) * LSTR + r] = v.z;
        xs[(kb + 3) * LSTR + r] = v.w;
    }
    __syncthreads();

    const int rg = tid % RG;
    const int cg = tid / RG;

    float acc[TM][TN];
#pragma unroll
    for (int j = 0; j < TM; ++j)
#pragma unroll
        for (int c = 0; c < TN; ++c) acc[j][c] = 0.f;

    const float4* W4 = (const float4*)W;
#pragma unroll 4
    for (int k = 0; k < K; ++k) {
        float a[TM];
        if constexpr (TM == 4) {
            float4 av = *(const float4*)&xs[k * LSTR + rg * 4];
            a[0] = av.x; a[1] = av.y; a[2] = av.z; a[3] = av.w;
        } else {
            float2 av = *(const float2*)&xs[k * LSTR + rg * 2];
            a[0] = av.x; a[1] = av.y;
        }
        float4 b0 = W4[k * (BN / 4) + cg * 2];
        float4 b1 = W4[k * (BN / 4) + cg * 2 + 1];
#pragma unroll
        for (int j = 0; j < TM; ++j) {
            acc[j][0] = fmaf(a[j], b0.x, acc[j][0]);
            acc[j][1] = fmaf(a[j], b0.y, acc[j][1]);
            acc[j][2] = fmaf(a[j], b0.z, acc[j][2]);
            acc[j][3] = fmaf(a[j], b0.w, acc[j][3]);
            acc[j][4] = fmaf(a[j], b1.x, acc[j][4]);
            acc[j][5] = fmaf(a[j], b1.y, acc[j][5]);
            acc[j][6] = fmaf(a[j], b1.z, acc[j][6]);
            acc[j][7] = fmaf(a[j], b1.w, acc[j][7]);
        }
    }

#pragma unroll
    for (int j = 0; j < TM; ++j) {
        int r = m0 + rg * TM + j;
        if (r < M) {
            float dv = dis[r];
            uint4 p;
            p.x = bf16_rne(acc[j][0] * dv) | (bf16_rne(acc[j][1] * dv) << 16);
            p.y = bf16_rne(acc[j][2] * dv) | (bf16_rne(acc[j][3] * dv) << 16);
            p.z = bf16_rne(acc[j][4] * dv) | (bf16_rne(acc[j][5] * dv) << 16);
            p.w = bf16_rne(acc[j][6] * dv) | (bf16_rne(acc[j][7] * dv) << 16);
            Hb[r * (BN / 8) + cg] = p;
        }
    }
}

// ====== Aggregate L1 (D=128): AGG[n] = dn*(sum Hs[src] + Hs[n]) + bias ======
// 512-thread blocks (full occupancy), unroll x16 for miss-level parallelism.

__global__ __launch_bounds__(512) void k_agg1(
    const int* __restrict__ rowptr, const int* __restrict__ csr,
    const float* __restrict__ dis, const u32* __restrict__ Hb,
    const float* __restrict__ bias, float* __restrict__ AGG, int N)
{
    int n = (blockIdx.x * 512 + threadIdx.x) >> 6;
    int lane = threadIdx.x & 63;
    if (n >= N) return;
    int e = rowptr[n];
    const int s1 = rowptr[n + 1];
    const float dn = dis[n];

    float a0 = 0.f, a1 = 0.f, b0 = 0.f, b1 = 0.f;
    float c0 = 0.f, c1 = 0.f, d0 = 0.f, d1 = 0.f;

    for (; e + 16 <= s1; e += 16) {
        int i0 = csr[e + 0],  i1 = csr[e + 1],  i2 = csr[e + 2],  i3 = csr[e + 3];
        int i4 = csr[e + 4],  i5 = csr[e + 5],  i6 = csr[e + 6],  i7 = csr[e + 7];
        int i8 = csr[e + 8],  i9 = csr[e + 9],  iA = csr[e + 10], iB = csr[e + 11];
        int iC = csr[e + 12], iD = csr[e + 13], iE = csr[e + 14], iF = csr[e + 15];
        u32 u0 = Hb[i0 * 64 + lane], u1 = Hb[i1 * 64 + lane];
        u32 u2 = Hb[i2 * 64 + lane], u3 = Hb[i3 * 64 + lane];
        u32 u4 = Hb[i4 * 64 + lane], u5 = Hb[i5 * 64 + lane];
        u32 u6 = Hb[i6 * 64 + lane], u7 = Hb[i7 * 64 + lane];
        u32 u8 = Hb[i8 * 64 + lane], u9 = Hb[i9 * 64 + lane];
        u32 uA = Hb[iA * 64 + lane], uB = Hb[iB * 64 + lane];
        u32 uC = Hb[iC * 64 + lane], uD = Hb[iD * 64 + lane];
        u32 uE = Hb[iE * 64 + lane], uF = Hb[iF * 64 + lane];
        a0 += (bf_lo(u0) + bf_lo(u4)) + (bf_lo(u8) + bf_lo(uC));
        a1 += (bf_hi(u0) + bf_hi(u4)) + (bf_hi(u8) + bf_hi(uC));
        b0 += (bf_lo(u1) + bf_lo(u5)) + (bf_lo(u9) + bf_lo(uD));
        b1 += (bf_hi(u1) + bf_hi(u5)) + (bf_hi(u9) + bf_hi(uD));
        c0 += (bf_lo(u2) + bf_lo(u6)) + (bf_lo(uA) + bf_lo(uE));
        c1 += (bf_hi(u2) + bf_hi(u6)) + (bf_hi(uA) + bf_hi(uE));
        d0 += (bf_lo(u3) + bf_lo(u7)) + (bf_lo(uB) + bf_lo(uF));
        d1 += (bf_hi(u3) + bf_hi(u7)) + (bf_hi(uB) + bf_hi(uF));
    }
    for (; e + 4 <= s1; e += 4) {
        int i0 = csr[e + 0], i1 = csr[e + 1], i2 = csr[e + 2], i3 = csr[e + 3];
        u32 u0 = Hb[i0 * 64 + lane], u1 = Hb[i1 * 64 + lane];
        u32 u2 = Hb[i2 * 64 + lane], u3 = Hb[i3 * 64 + lane];
        a0 += bf_lo(u0); a1 += bf_hi(u0);
        b0 += bf_lo(u1); b1 += bf_hi(u1);
        c0 += bf_lo(u2); c1 += bf_hi(u2);
        d0 += bf_lo(u3); d1 += bf_hi(u3);
    }
    for (; e < s1; ++e) {
        u32 u = Hb[csr[e] * 64 + lane];
        a0 += bf_lo(u); a1 += bf_hi(u);
    }

    u32 self = Hb[n * 64 + lane];
    float2 bv = ((const float2*)bias)[lane];
    float2 o;
    o.x = fmaf(dn, (a0 + b0) + (c0 + d0) + bf_lo(self), bv.x);
    o.y = fmaf(dn, (a1 + b1) + (c1 + d1) + bf_hi(self), bv.y);
    ((float2*)AGG)[n * 64 + lane] = o;
}

// ====== Aggregate L2 (D=64) ======

__global__ __launch_bounds__(512) void k_agg2(
    const int* __restrict__ rowptr, const int* __restrict__ csr,
    const float* __restrict__ dis, const u16* __restrict__ Hb,
    const float* __restrict__ bias, float* __restrict__ AGG, int N)
{
    int n = (blockIdx.x * 512 + threadIdx.x) >> 6;
    int lane = threadIdx.x & 63;
    if (n >= N) return;
    int e = rowptr[n];
    const int s1 = rowptr[n + 1];
    const float dn = dis[n];

    float a0 = 0.f, b0 = 0.f, c0 = 0.f, d0 = 0.f;

    for (; e + 16 <= s1; e += 16) {
        int i0 = csr[e + 0],  i1 = csr[e + 1],  i2 = csr[e + 2],  i3 = csr[e + 3];
        int i4 = csr[e + 4],  i5 = csr[e + 5],  i6 = csr[e + 6],  i7 = csr[e + 7];
        int i8 = csr[e + 8],  i9 = csr[e + 9],  iA = csr[e + 10], iB = csr[e + 11];
        int iC = csr[e + 12], iD = csr[e + 13], iE = csr[e + 14], iF = csr[e + 15];
        float v0 = __uint_as_float((u32)Hb[i0 * 64 + lane] << 16);
        float v1 = __uint_as_float((u32)Hb[i1 * 64 + lane] << 16);
        float v2 = __uint_as_float((u32)Hb[i2 * 64 + lane] << 16);
        float v3 = __uint_as_float((u32)Hb[i3 * 64 + lane] << 16);
        float v4 = __uint_as_float((u32)Hb[i4 * 64 + lane] << 16);
        float v5 = __uint_as_float((u32)Hb[i5 * 64 + lane] << 16);
        float v6 = __uint_as_float((u32)Hb[i6 * 64 + lane] << 16);
        float v7 = __uint_as_float((u32)Hb[i7 * 64 + lane] << 16);
        float v8 = __uint_as_float((u32)Hb[i8 * 64 + lane] << 16);
        float v9 = __uint_as_float((u32)Hb[i9 * 64 + lane] << 16);
        float vA = __uint_as_float((u32)Hb[iA * 64 + lane] << 16);
        float vB = __uint_as_float((u32)Hb[iB * 64 + lane] << 16);
        float vC = __uint_as_float((u32)Hb[iC * 64 + lane] << 16);
        float vD = __uint_as_float((u32)Hb[iD * 64 + lane] << 16);
        float vE = __uint_as_float((u32)Hb[iE * 64 + lane] << 16);
        float vF = __uint_as_float((u32)Hb[iF * 64 + lane] << 16);
        a0 += (v0 + v4) + (v8 + vC);
        b0 += (v1 + v5) + (v9 + vD);
        c0 += (v2 + v6) + (vA + vE);
        d0 += (v3 + v7) + (vB + vF);
    }
    for (; e + 4 <= s1; e += 4) {
        int i0 = csr[e + 0], i1 = csr[e + 1], i2 = csr[e + 2], i3 = csr[e + 3];
        a0 += __uint_as_float((u32)Hb[i0 * 64 + lane] << 16);
        b0 += __uint_as_float((u32)Hb[i1 * 64 + lane] << 16);
        c0 += __uint_as_float((u32)Hb[i2 * 64 + lane] << 16);
        d0 += __uint_as_float((u32)Hb[i3 * 64 + lane] << 16);
    }
    for (; e < s1; ++e)
        a0 += __uint_as_float((u32)Hb[csr[e] * 64 + lane] << 16);

    float self = __uint_as_float((u32)Hb[n * 64 + lane] << 16);
    AGG[n * 64 + lane] = fmaf(dn, (a0 + b0) + (c0 + d0) + self, bias[lane]);
}

// ================= mean pool over sorted batch =================

__device__ inline int lower_bound(const int* __restrict__ b, int n, int v) {
    int lo = 0, hi = n;
    while (lo < hi) { int m = (lo + hi) >> 1; if (b[m] < v) lo = m + 1; else hi = m; }
    return lo;
}

__global__ __launch_bounds__(256) void k_pool(
    const int* __restrict__ batch, const float* __restrict__ AGG2,
    float* __restrict__ G, int n)
{
    int g = blockIdx.x;
    int start = lower_bound(batch, n, g);
    int end   = lower_bound(batch, n, g + 1);
    int tid = threadIdx.x;
    int f = tid & 63, stripe = tid >> 6;
    float acc = 0.f;
    for (int i = start + stripe; i < end; i += 4)
        acc += AGG2[(size_t)i * 64 + f];
    __shared__ float red[256];
    red[tid] = acc;
    __syncthreads();
    if (tid < 64) {
        float s = red[tid] + red[tid + 64] + red[tid + 128] + red[tid + 192];
        float c = (float)(end - start);
        G[g * 64 + tid] = s / fmaxf(c, 1.0f);
    }
}

// ================= classifier =================

__global__ __launch_bounds__(256) void k_fc(
    const float* __restrict__ G, const float* __restrict__ Wfc,
    const float* __restrict__ bfc, float* __restrict__ out, int ng)
{
    __shared__ float wl[640];
    __shared__ float bl[10];
    int tid = threadIdx.x;
    for (int i = tid; i < 640; i += 256) wl[i] = Wfc[i];
    if (tid < 10) bl[tid] = bfc[tid];
    __syncthreads();
    if (tid >= ng) return;
    float acc[10];
#pragma unroll
    for (int c = 0; c < 10; ++c) acc[c] = bl[c];
    for (int k = 0; k < 64; ++k) {
        float gv = G[tid * 64 + k];
#pragma unroll
        for (int c = 0; c < 10; ++c) acc[c] = fmaf(gv, wl[k * 10 + c], acc[c]);
    }
#pragma unroll
    for (int c = 0; c < 10; ++c) out[tid * 10 + c] = acc[c];
}

// ================= launch =================

extern "C" void kernel_launch(void* const* d_in, const int* in_sizes, int n_in,
                              void* d_out, int out_size, void* d_ws, size_t ws_size,
                              hipStream_t stream)
{
    const float* x    = (const float*)d_in[0];
    const int*   ei   = (const int*)d_in[1];
    const int*   batch= (const int*)d_in[2];
    const float* W1   = (const float*)d_in[3];
    const float* b1   = (const float*)d_in[4];
    const float* W2   = (const float*)d_in[5];
    const float* b2   = (const float*)d_in[6];
    const float* Wfc  = (const float*)d_in[7];
    const float* bfc  = (const float*)d_in[8];
    float* out = (float*)d_out;

    const int N  = in_sizes[0] / 128;     // 100000
    const int E  = in_sizes[1] / 2;       // 3200000
    const int ng = out_size / 10;         // 256

    const int NBK = (N + BKW - 1) / BKW;  // 98 buckets

    // ---- workspace layout (words) ----
    int*   rowptr    = (int*)d_ws;                          // 102400 (N+1)
    int*   bucketCur = rowptr + 102400;                     // 256
    float* dis       = (float*)(bucketCur + 256);           // 102400
    int*   csr       = (int*)(dis + 102400);                // E
    // region A (6.4M words): tmp (NBK*CAP=3.61M) -> Hb1 (N*64) -> agg2 (N*64)
    u32*   tmp       = (u32*)(csr + E);
    u32*   Hb1       = tmp;
    float* agg2      = (float*)tmp;
    float* agg1      = (float*)((int*)tmp + (size_t)N * 64);    // N*128
    u16*   Hb2       = (u16*)(agg1 + (size_t)N * 128);          // N*64 u16
    float* g         = (float*)((int*)Hb2 + (size_t)N * 32);    // ng*64

    // ---- CSR build: radix partition ----
    k_zero_small<<<1, 128, 0, stream>>>(bucketCur, NBK);
    k_part1<<<(E + TILE1 - 1) / TILE1, 256, 0, stream>>>(ei, bucketCur, tmp, E, N, NBK);
    k_part2<<<NBK, 256, 0, stream>>>(bucketCur, tmp, csr, rowptr, dis, N, NBK);

    // ---- layer 1 ----
    k_gemm<64, 128, 4, false><<<(N + 63) / 64, 256, 0, stream>>>(x, W1, dis, (uint4*)Hb1, N);
    k_agg1<<<(N + 7) / 8, 512, 0, stream>>>(rowptr, csr, dis, Hb1, b1, agg1, N);

    // ---- layer 2 ----
    k_gemm<64, 64, 2, true><<<(N + 63) / 64, 256, 0, stream>>>(agg1, W2, dis, (uint4*)Hb2, N);
    k_agg2<<<(N + 7) / 8, 512, 0, stream>>>(rowptr, csr, dis, Hb2, b2, agg2, N);

    // ---- pool + classifier ----
    k_pool<<<ng, 256, 0, stream>>>(batch, agg2, g, N);
    k_fc<<<1, 256, 0, stream>>>(g, Wfc, bfc, out, ng);
}

// Round 8
// 553.659 us; speedup vs baseline: 2.1826x; 1.0501x over previous
//
#include <hip/hip_runtime.h>
#include <math.h>

typedef unsigned int  u32;
typedef unsigned short u16;

#define TILE1 4096      // edges per pass-1 block (16/thread)
#define BKW   1024      // nodes per bucket (shift 10)
#define CAP   36864     // tmp slots per bucket (mean 32653, +22 sigma)

__device__ inline u32 bf16_rne(float f) {
    u32 u = __float_as_uint(f);
    return (u + 0x7FFFu + ((u >> 16) & 1u)) >> 16;
}
__device__ inline float bf_lo(u32 u) { return __uint_as_float(u << 16); }
__device__ inline float bf_hi(u32 u) { return __uint_as_float(u & 0xFFFF0000u); }

__device__ inline void add8(float* acc, uint4 q) {
    acc[0] += bf_lo(q.x); acc[1] += bf_hi(q.x);
    acc[2] += bf_lo(q.y); acc[3] += bf_hi(q.y);
    acc[4] += bf_lo(q.z); acc[5] += bf_hi(q.z);
    acc[6] += bf_lo(q.w); acc[7] += bf_hi(q.w);
}

// ================= CSR build: 2-pass radix partition =================

// pass 1: partition edges into buckets of 1024 dst nodes.
// packed value = (dstLocal<<17) | src   (src < 2^17, dstLocal < 1024)
__global__ __launch_bounds__(256) void k_part1(const int* __restrict__ ei,
                                               int* __restrict__ bucketCur,
                                               u32* __restrict__ tmp,
                                               int E, int N, int NBK) {
    __shared__ int hist[128];
    __shared__ int base[128];
    const int tid = threadIdx.x;
    if (tid < NBK) hist[tid] = 0;
    __syncthreads();

    const int t0 = blockIdx.x * TILE1;
    int sv[16], dv[16], key[16];
#pragma unroll
    for (int j = 0; j < 16; ++j) {
        int i = t0 + j * 256 + tid;
        key[j] = -1;
        if (i < E) {
            sv[j] = ei[i];
            dv[j] = ei[E + i];
            if ((unsigned)dv[j] < (unsigned)N && (unsigned)sv[j] < (unsigned)N) {
                key[j] = dv[j] >> 10;
                atomicAdd(&hist[key[j]], 1);
            }
        }
    }
    __syncthreads();
    if (tid < NBK) {
        base[tid] = atomicAdd(&bucketCur[tid], hist[tid]);
        hist[tid] = 0;                 // reuse as running cursor
    }
    __syncthreads();
#pragma unroll
    for (int j = 0; j < 16; ++j) {
        if (key[j] >= 0) {
            int slot = atomicAdd(&hist[key[j]], 1);
            int off = base[key[j]] + slot;
            if (off < CAP)
                tmp[(size_t)key[j] * CAP + off] =
                    ((u32)(dv[j] & 1023) << 17) | (u32)sv[j];
        }
    }
}

// pass 2: one block per bucket. scan bucket counts (inline), histogram ->
// rowptr + dis, then place csr with LDS cursors.
__global__ __launch_bounds__(256) void k_part2(const int* __restrict__ bucketCnt,
                                               const u32* __restrict__ tmp,
                                               int* __restrict__ csr,
                                               int* __restrict__ rowptr,
                                               float* __restrict__ dis,
                                               int N, int NBK) {
    __shared__ int hist[1024];
    __shared__ int ts[256];
    __shared__ int sStart;
    const int b = blockIdx.x;
    const int t = threadIdx.x;

    // inline exclusive scan of bucketCnt to get this bucket's start
    int myCnt = (t < NBK) ? bucketCnt[t] : 0;
    ts[t] = myCnt;
    __syncthreads();
    for (int off = 1; off < 256; off <<= 1) {
        int u = (t >= off) ? ts[t - off] : 0;
        __syncthreads();
        ts[t] += u;
        __syncthreads();
    }
    if (t == b) sStart = ts[t] - myCnt;
    if (b == 0 && t == NBK - 1) rowptr[N] = ts[t];
    __syncthreads();
    const int start = sStart;
    const int cnt = bucketCnt[b];
    const u32* src = tmp + (size_t)b * CAP;

    for (int i = t; i < 1024; i += 256) hist[i] = 0;
    __syncthreads();
    for (int i = t; i < cnt; i += 256)
        atomicAdd(&hist[src[i] >> 17], 1);
    __syncthreads();

    // exclusive scan of hist[0..1023]
    int h0 = hist[t * 4], h1 = hist[t * 4 + 1], h2 = hist[t * 4 + 2], h3 = hist[t * 4 + 3];
    int s = h0 + h1 + h2 + h3;
    ts[t] = s;
    __syncthreads();
    for (int off = 1; off < 256; off <<= 1) {
        int u = (t >= off) ? ts[t - off] : 0;
        __syncthreads();
        ts[t] += u;
        __syncthreads();
    }
    int ex = ts[t] - s;
    hist[t * 4]     = ex;
    hist[t * 4 + 1] = ex + h0;
    hist[t * 4 + 2] = ex + h0 + h1;
    hist[t * 4 + 3] = ex + h0 + h1 + h2;
    __syncthreads();

    // rowptr + dis for this bucket's nodes
    const int nbase = b << 10;
    for (int l = t; l < 1024; l += 256) {
        int gn = nbase + l;
        if (gn < N) {
            int e0 = hist[l];
            int e1 = (l < 1023) ? hist[l + 1] : cnt;
            rowptr[gn] = start + e0;
            dis[gn] = rsqrtf((float)(e1 - e0) + 1.0f);
        }
    }
    __syncthreads();

    // place (hist becomes running cursor)
    for (int i = t; i < cnt; i += 256) {
        u32 v = src[i];
        int p = atomicAdd(&hist[v >> 17], 1);
        csr[start + p] = (int)(v & 0x1FFFFu);
    }
}

// ========== GEMM: Hb = bf16( (X @ W) * dis[row] ), packed 2 cols/uint ==========

template <int BM, int BN, int TM, bool RELU_IN>
__global__ __launch_bounds__(256) void k_gemm(
    const float* __restrict__ X, const float* __restrict__ W,
    const float* __restrict__ dis, uint4* __restrict__ Hb, int M)
{
    constexpr int K = 128;
    constexpr int TN = 8;
    constexpr int RG = BM / TM;
    constexpr int LSTR = BM + 4;
    __shared__ float xs[K * LSTR];

    const int tid = threadIdx.x;
    const int m0 = blockIdx.x * BM;

    const float4* X4 = (const float4*)X;
    constexpr int NV = BM * (K / 4) / 256;
#pragma unroll
    for (int i = 0; i < NV; ++i) {
        int idx = tid + i * 256;
        int r = idx >> 5;
        int kq = idx & 31;
        float4 v = make_float4(0.f, 0.f, 0.f, 0.f);
        int gr = m0 + r;
        if (gr < M) v = X4[gr * 32 + kq];
        if (RELU_IN) {
            v.x = fmaxf(v.x, 0.f); v.y = fmaxf(v.y, 0.f);
            v.z = fmaxf(v.z, 0.f); v.w = fmaxf(v.w, 0.f);
        }
        int kb = kq * 4;
        xs[(kb + 0) * LSTR + r] = v.x;
        xs[(kb + 1) * LSTR + r] = v.y;
        xs[(kb + 2) * LSTR + r] = v.z;
        xs[(kb + 3) * LSTR + r] = v.w;
    }
    __syncthreads();

    const int rg = tid % RG;
    const int cg = tid / RG;

    float acc[TM][TN];
#pragma unroll
    for (int j = 0; j < TM; ++j)
#pragma unroll
        for (int c = 0; c < TN; ++c) acc[j][c] = 0.f;

    const float4* W4 = (const float4*)W;
#pragma unroll 4
    for (int k = 0; k < K; ++k) {
        float a[TM];
        if constexpr (TM == 4) {
            float4 av = *(const float4*)&xs[k * LSTR + rg * 4];
            a[0] = av.x; a[1] = av.y; a[2] = av.z; a[3] = av.w;
        } else {
            float2 av = *(const float2*)&xs[k * LSTR + rg * 2];
            a[0] = av.x; a[1] = av.y;
        }
        float4 b0 = W4[k * (BN / 4) + cg * 2];
        float4 b1 = W4[k * (BN / 4) + cg * 2 + 1];
#pragma unroll
        for (int j = 0; j < TM; ++j) {
            acc[j][0] = fmaf(a[j], b0.x, acc[j][0]);
            acc[j][1] = fmaf(a[j], b0.y, acc[j][1]);
            acc[j][2] = fmaf(a[j], b0.z, acc[j][2]);
            acc[j][3] = fmaf(a[j], b0.w, acc[j][3]);
            acc[j][4] = fmaf(a[j], b1.x, acc[j][4]);
            acc[j][5] = fmaf(a[j], b1.y, acc[j][5]);
            acc[j][6] = fmaf(a[j], b1.z, acc[j][6]);
            acc[j][7] = fmaf(a[j], b1.w, acc[j][7]);
        }
    }

#pragma unroll
    for (int j = 0; j < TM; ++j) {
        int r = m0 + rg * TM + j;
        if (r < M) {
            float dv = dis[r];
            uint4 p;
            p.x = bf16_rne(acc[j][0] * dv) | (bf16_rne(acc[j][1] * dv) << 16);
            p.y = bf16_rne(acc[j][2] * dv) | (bf16_rne(acc[j][3] * dv) << 16);
            p.z = bf16_rne(acc[j][4] * dv) | (bf16_rne(acc[j][5] * dv) << 16);
            p.w = bf16_rne(acc[j][6] * dv) | (bf16_rne(acc[j][7] * dv) << 16);
            Hb[r * (BN / 8) + cg] = p;
        }
    }
}

// ====== Aggregate L1 (D=128): wave per node, 4 edges per wave-instr.
// lane = (slot 0-3, li 0-15); lane reads uint4 (8 bf16 cols) of its slot's
// edge; butterfly xor-16/32 folds slots at the end. Self row = tail slot.

__global__ __launch_bounds__(256) void k_agg1(
    const int* __restrict__ rowptr, const int* __restrict__ csr,
    const float* __restrict__ dis, const uint4* __restrict__ Hb4,
    const float* __restrict__ bias, float* __restrict__ AGG, int N)
{
    int n = (blockIdx.x * 256 + threadIdx.x) >> 6;
    int lane = threadIdx.x & 63;
    int slot = lane >> 4;        // 0..3
    int li   = lane & 15;        // uint4 index within row (16 * 16B = 256B)
    if (n >= N) return;
    int e = rowptr[n];
    const int s1 = rowptr[n + 1];
    const float dn = dis[n];

    float acc[8];
#pragma unroll
    for (int j = 0; j < 8; ++j) acc[j] = 0.f;

    // 16 edges per iteration: 4 per slot
    for (; e + 16 <= s1; e += 16) {
        int i0 = csr[e + slot];
        int i1 = csr[e + 4 + slot];
        int i2 = csr[e + 8 + slot];
        int i3 = csr[e + 12 + slot];
        uint4 q0 = Hb4[(size_t)i0 * 16 + li];
        uint4 q1 = Hb4[(size_t)i1 * 16 + li];
        uint4 q2 = Hb4[(size_t)i2 * 16 + li];
        uint4 q3 = Hb4[(size_t)i3 * 16 + li];
        add8(acc, q0); add8(acc, q1); add8(acc, q2); add8(acc, q3);
    }
    for (; e + 4 <= s1; e += 4) {
        int i0 = csr[e + slot];
        uint4 q0 = Hb4[(size_t)i0 * 16 + li];
        add8(acc, q0);
    }
    // tail (rem 0..3 edges) + self row merged
    {
        int rem = s1 - e;
        int idx = -1;
        if (slot < rem) idx = csr[e + slot];
        else if (slot == rem) idx = n;          // self-loop row
        if (idx >= 0) {
            uint4 q = Hb4[(size_t)idx * 16 + li];
            add8(acc, q);
        }
    }

    // fold the 4 slots
#pragma unroll
    for (int j = 0; j < 8; ++j) {
        acc[j] += __shfl_xor(acc[j], 16, 64);
        acc[j] += __shfl_xor(acc[j], 32, 64);
    }

    // lanes slot 0-1 write: slot s stores cols [8li + 4s, 8li + 4s + 4)
    if (slot < 2) {
        float4 bv = ((const float4*)bias)[li * 2 + slot];
        float4 o;
        o.x = fmaf(dn, acc[4 * slot + 0], bv.x);
        o.y = fmaf(dn, acc[4 * slot + 1], bv.y);
        o.z = fmaf(dn, acc[4 * slot + 2], bv.z);
        o.w = fmaf(dn, acc[4 * slot + 3], bv.w);
        ((float4*)AGG)[(size_t)n * 32 + li * 2 + slot] = o;
    }
}

// ====== Aggregate L2 (D=64): 8 edges per wave-instr (8 lanes x uint4/edge) ======

__global__ __launch_bounds__(256) void k_agg2(
    const int* __restrict__ rowptr, const int* __restrict__ csr,
    const float* __restrict__ dis, const uint4* __restrict__ Hb4,
    const float* __restrict__ bias, float* __restrict__ AGG, int N)
{
    int n = (blockIdx.x * 256 + threadIdx.x) >> 6;
    int lane = threadIdx.x & 63;
    int slot = lane >> 3;        // 0..7
    int li   = lane & 7;         // uint4 index within row (8 * 16B = 128B)
    if (n >= N) return;
    int e = rowptr[n];
    const int s1 = rowptr[n + 1];
    const float dn = dis[n];

    float acc[8];
#pragma unroll
    for (int j = 0; j < 8; ++j) acc[j] = 0.f;

    // 16 edges per iteration: 2 per slot
    for (; e + 16 <= s1; e += 16) {
        int i0 = csr[e + slot];
        int i1 = csr[e + 8 + slot];
        uint4 q0 = Hb4[(size_t)i0 * 8 + li];
        uint4 q1 = Hb4[(size_t)i1 * 8 + li];
        add8(acc, q0); add8(acc, q1);
    }
    for (; e + 8 <= s1; e += 8) {
        int i0 = csr[e + slot];
        uint4 q0 = Hb4[(size_t)i0 * 8 + li];
        add8(acc, q0);
    }
    // tail (rem 0..7) + self merged
    {
        int rem = s1 - e;
        int idx = -1;
        if (slot < rem) idx = csr[e + slot];
        else if (slot == rem) idx = n;
        if (idx >= 0) {
            uint4 q = Hb4[(size_t)idx * 8 + li];
            add8(acc, q);
        }
    }

    // fold the 8 slots
#pragma unroll
    for (int j = 0; j < 8; ++j) {
        acc[j] += __shfl_xor(acc[j], 8, 64);
        acc[j] += __shfl_xor(acc[j], 16, 64);
        acc[j] += __shfl_xor(acc[j], 32, 64);
    }

    if (slot < 2) {
        float4 bv = ((const float4*)bias)[li * 2 + slot];
        float4 o;
        o.x = fmaf(dn, acc[4 * slot + 0], bv.x);
        o.y = fmaf(dn, acc[4 * slot + 1], bv.y);
        o.z = fmaf(dn, acc[4 * slot + 2], bv.z);
        o.w = fmaf(dn, acc[4 * slot + 3], bv.w);
        ((float4*)AGG)[(size_t)n * 16 + li * 2 + slot] = o;
    }
}

// ================= mean pool over sorted batch =================

__device__ inline int lower_bound(const int* __restrict__ b, int n, int v) {
    int lo = 0, hi = n;
    while (lo < hi) { int m = (lo + hi) >> 1; if (b[m] < v) lo = m + 1; else hi = m; }
    return lo;
}

__global__ __launch_bounds__(256) void k_pool(
    const int* __restrict__ batch, const float* __restrict__ AGG2,
    float* __restrict__ G, int n)
{
    int g = blockIdx.x;
    int start = lower_bound(batch, n, g);
    int end   = lower_bound(batch, n, g + 1);
    int tid = threadIdx.x;
    int f = tid & 63, stripe = tid >> 6;
    float acc = 0.f;
    for (int i = start + stripe; i < end; i += 4)
        acc += AGG2[(size_t)i * 64 + f];
    __shared__ float red[256];
    red[tid] = acc;
    __syncthreads();
    if (tid < 64) {
        float s = red[tid] + red[tid + 64] + red[tid + 128] + red[tid + 192];
        float c = (float)(end - start);
        G[g * 64 + tid] = s / fmaxf(c, 1.0f);
    }
}

// ================= classifier =================

__global__ __launch_bounds__(256) void k_fc(
    const float* __restrict__ G, const float* __restrict__ Wfc,
    const float* __restrict__ bfc, float* __restrict__ out, int ng)
{
    __shared__ float wl[640];
    __shared__ float bl[10];
    int tid = threadIdx.x;
    for (int i = tid; i < 640; i += 256) wl[i] = Wfc[i];
    if (tid < 10) bl[tid] = bfc[tid];
    __syncthreads();
    if (tid >= ng) return;
    float acc[10];
#pragma unroll
    for (int c = 0; c < 10; ++c) acc[c] = bl[c];
    for (int k = 0; k < 64; ++k) {
        float gv = G[tid * 64 + k];
#pragma unroll
        for (int c = 0; c < 10; ++c) acc[c] = fmaf(gv, wl[k * 10 + c], acc[c]);
    }
#pragma unroll
    for (int c = 0; c < 10; ++c) out[tid * 10 + c] = acc[c];
}

// ================= launch =================

extern "C" void kernel_launch(void* const* d_in, const int* in_sizes, int n_in,
                              void* d_out, int out_size, void* d_ws, size_t ws_size,
                              hipStream_t stream)
{
    const float* x    = (const float*)d_in[0];
    const int*   ei   = (const int*)d_in[1];
    const int*   batch= (const int*)d_in[2];
    const float* W1   = (const float*)d_in[3];
    const float* b1   = (const float*)d_in[4];
    const float* W2   = (const float*)d_in[5];
    const float* b2   = (const float*)d_in[6];
    const float* Wfc  = (const float*)d_in[7];
    const float* bfc  = (const float*)d_in[8];
    float* out = (float*)d_out;

    const int N  = in_sizes[0] / 128;     // 100000
    const int E  = in_sizes[1] / 2;       // 3200000
    const int ng = out_size / 10;         // 256

    const int NBK = (N + BKW - 1) / BKW;  // 98 buckets

    // ---- workspace layout (words) ----
    int*   rowptr    = (int*)d_ws;                          // 102400 (N+1)
    int*   bucketCur = rowptr + 102400;                     // 256
    float* dis       = (float*)(bucketCur + 256);           // 102400
    int*   csr       = (int*)(dis + 102400);                // E
    // region A (6.4M words): tmp (NBK*CAP=3.61M) -> Hb1 (N*64) -> agg2 (N*64)
    u32*   tmp       = (u32*)(csr + E);
    u32*   Hb1       = tmp;
    float* agg2      = (float*)tmp;
    float* agg1      = (float*)((int*)tmp + (size_t)N * 64);    // N*128
    u16*   Hb2       = (u16*)(agg1 + (size_t)N * 128);          // N*64 u16
    float* g         = (float*)((int*)Hb2 + (size_t)N * 32);    // ng*64

    // ---- CSR build: radix partition ----
    hipMemsetAsync(bucketCur, 0, NBK * sizeof(int), stream);
    k_part1<<<(E + TILE1 - 1) / TILE1, 256, 0, stream>>>(ei, bucketCur, tmp, E, N, NBK);
    k_part2<<<NBK, 256, 0, stream>>>(bucketCur, tmp, csr, rowptr, dis, N, NBK);

    // ---- layer 1 ----
    k_gemm<64, 128, 4, false><<<(N + 63) / 64, 256, 0, stream>>>(x, W1, dis, (uint4*)Hb1, N);
    k_agg1<<<(N + 3) / 4, 256, 0, stream>>>(rowptr, csr, dis, (const uint4*)Hb1, b1, agg1, N);

    // ---- layer 2 ----
    k_gemm<64, 64, 2, true><<<(N + 63) / 64, 256, 0, stream>>>(agg1, W2, dis, (uint4*)Hb2, N);
    k_agg2<<<(N + 3) / 4, 256, 0, stream>>>(rowptr, csr, dis, (const uint4*)Hb2, b2, agg2, N);

    // ---- pool + classifier ----
    k_pool<<<ng, 256, 0, stream>>>(batch, agg2, g, N);
    k_fc<<<1, 256, 0, stream>>>(g, Wfc, bfc, out, ng);
}

// Round 9
// 494.832 us; speedup vs baseline: 2.4420x; 1.1189x over previous
//
#include <hip/hip_runtime.h>
#include <math.h>

typedef unsigned int  u32;
typedef unsigned short u16;

#define TILE1 8192      // edges per pass-1 block (16/thread @ 512 threads)
#define BKW   256       // nodes per bucket (shift 8)
#define CAP   9216      // tmp slots per bucket (mean 8192, +11 sigma)

__device__ inline u32 bf16_rne(float f) {
    u32 u = __float_as_uint(f);
    return (u + 0x7FFFu + ((u >> 16) & 1u)) >> 16;
}
__device__ inline float bf_lo(u32 u) { return __uint_as_float(u << 16); }
__device__ inline float bf_hi(u32 u) { return __uint_as_float(u & 0xFFFF0000u); }

__device__ inline void add8(float* acc, uint4 q) {
    acc[0] += bf_lo(q.x); acc[1] += bf_hi(q.x);
    acc[2] += bf_lo(q.y); acc[3] += bf_hi(q.y);
    acc[4] += bf_lo(q.z); acc[5] += bf_hi(q.z);
    acc[6] += bf_lo(q.w); acc[7] += bf_hi(q.w);
}

// ================= CSR build: 2-pass radix partition =================
// pass 1: partition edges into buckets of 256 dst nodes.
// packed value = (dstLocal<<17) | src   (src < 2^17, dstLocal < 256)

__global__ __launch_bounds__(512) void k_part1(const int* __restrict__ ei,
                                               int* __restrict__ bucketCur,
                                               u32* __restrict__ tmp,
                                               int E, int N, int NBK) {
    __shared__ int hist[512];
    __shared__ int base[512];
    const int tid = threadIdx.x;
    if (tid < NBK) hist[tid] = 0;
    __syncthreads();

    const int t0 = blockIdx.x * TILE1;
    int sv[16], dv[16], key[16];
#pragma unroll
    for (int j = 0; j < 16; ++j) {
        int i = t0 + j * 512 + tid;
        key[j] = -1;
        if (i < E) {
            sv[j] = ei[i];
            dv[j] = ei[E + i];
            if ((unsigned)dv[j] < (unsigned)N && (unsigned)sv[j] < (unsigned)N) {
                key[j] = dv[j] >> 8;
                atomicAdd(&hist[key[j]], 1);
            }
        }
    }
    __syncthreads();
    if (tid < NBK) {
        base[tid] = atomicAdd(&bucketCur[tid], hist[tid]);
        hist[tid] = 0;                 // reuse as running cursor
    }
    __syncthreads();
#pragma unroll
    for (int j = 0; j < 16; ++j) {
        if (key[j] >= 0) {
            int slot = atomicAdd(&hist[key[j]], 1);
            int off = base[key[j]] + slot;
            if (off < CAP)
                tmp[(size_t)key[j] * CAP + off] =
                    ((u32)(dv[j] & 255) << 17) | (u32)sv[j];
        }
    }
}

// pass 2: one block per bucket. inline scan of bucket counts, 256-entry
// histogram -> rowptr + dis, then place csr with LDS cursors.
__global__ __launch_bounds__(512) void k_part2(const int* __restrict__ bucketCnt,
                                               const u32* __restrict__ tmp,
                                               int* __restrict__ csr,
                                               int* __restrict__ rowptr,
                                               float* __restrict__ dis,
                                               int N, int NBK) {
    __shared__ int hist[256];
    __shared__ int ts[512];
    __shared__ int sStart;
    const int b = blockIdx.x;
    const int t = threadIdx.x;

    // exclusive scan of bucketCnt (NBK <= 512) to get this bucket's start
    int myCnt = (t < NBK) ? bucketCnt[t] : 0;
    ts[t] = myCnt;
    __syncthreads();
    for (int off = 1; off < 512; off <<= 1) {
        int u = (t >= off) ? ts[t - off] : 0;
        __syncthreads();
        ts[t] += u;
        __syncthreads();
    }
    if (t == b) sStart = ts[t] - myCnt;
    if (b == 0 && t == NBK - 1) rowptr[N] = ts[t];
    __syncthreads();
    const int start = sStart;
    const int cnt = bucketCnt[b];
    const u32* src = tmp + (size_t)b * CAP;

    if (t < 256) hist[t] = 0;
    __syncthreads();
    for (int i = t; i < cnt; i += 512)
        atomicAdd(&hist[src[i] >> 17], 1);
    __syncthreads();

    // exclusive scan of hist[0..255] (all threads hit barriers)
    int h = (t < 256) ? hist[t] : 0;
    ts[t] = h;
    __syncthreads();
    for (int off = 1; off < 512; off <<= 1) {
        int u = (t >= off) ? ts[t - off] : 0;
        __syncthreads();
        ts[t] += u;
        __syncthreads();
    }
    if (t < 256) hist[t] = ts[t] - h;       // exclusive
    __syncthreads();

    // rowptr + dis for this bucket's nodes
    if (t < 256) {
        int gn = (b << 8) + t;
        if (gn < N) {
            int e0 = hist[t];
            int e1 = (t < 255) ? hist[t + 1] : cnt;
            rowptr[gn] = start + e0;
            dis[gn] = rsqrtf((float)(e1 - e0) + 1.0f);
        }
    }
    __syncthreads();

    // place (hist becomes running cursor)
    for (int i = t; i < cnt; i += 512) {
        u32 v = src[i];
        int p = atomicAdd(&hist[v >> 17], 1);
        csr[start + p] = (int)(v & 0x1FFFFu);
    }
}

// ========== GEMM: Hb = bf16( (X @ W) * dis[row] ), packed 2 cols/uint ==========

template <int BM, int BN, int TM, bool RELU_IN>
__global__ __launch_bounds__(256) void k_gemm(
    const float* __restrict__ X, const float* __restrict__ W,
    const float* __restrict__ dis, uint4* __restrict__ Hb, int M)
{
    constexpr int K = 128;
    constexpr int TN = 8;
    constexpr int RG = BM / TM;
    constexpr int LSTR = BM + 4;
    __shared__ float xs[K * LSTR];

    const int tid = threadIdx.x;
    const int m0 = blockIdx.x * BM;

    const float4* X4 = (const float4*)X;
    constexpr int NV = BM * (K / 4) / 256;
#pragma unroll
    for (int i = 0; i < NV; ++i) {
        int idx = tid + i * 256;
        int r = idx >> 5;
        int kq = idx & 31;
        float4 v = make_float4(0.f, 0.f, 0.f, 0.f);
        int gr = m0 + r;
        if (gr < M) v = X4[gr * 32 + kq];
        if (RELU_IN) {
            v.x = fmaxf(v.x, 0.f); v.y = fmaxf(v.y, 0.f);
            v.z = fmaxf(v.z, 0.f); v.w = fmaxf(v.w, 0.f);
        }
        int kb = kq * 4;
        xs[(kb + 0) * LSTR + r] = v.x;
        xs[(kb + 1) * LSTR + r] = v.y;
        xs[(kb + 2) * LSTR + r] = v.z;
        xs[(kb + 3) * LSTR + r] = v.w;
    }
    __syncthreads();

    const int rg = tid % RG;
    const int cg = tid / RG;

    float acc[TM][TN];
#pragma unroll
    for (int j = 0; j < TM; ++j)
#pragma unroll
        for (int c = 0; c < TN; ++c) acc[j][c] = 0.f;

    const float4* W4 = (const float4*)W;
#pragma unroll 4
    for (int k = 0; k < K; ++k) {
        float a[TM];
        if constexpr (TM == 4) {
            float4 av = *(const float4*)&xs[k * LSTR + rg * 4];
            a[0] = av.x; a[1] = av.y; a[2] = av.z; a[3] = av.w;
        } else {
            float2 av = *(const float2*)&xs[k * LSTR + rg * 2];
            a[0] = av.x; a[1] = av.y;
        }
        float4 b0 = W4[k * (BN / 4) + cg * 2];
        float4 b1 = W4[k * (BN / 4) + cg * 2 + 1];
#pragma unroll
        for (int j = 0; j < TM; ++j) {
            acc[j][0] = fmaf(a[j], b0.x, acc[j][0]);
            acc[j][1] = fmaf(a[j], b0.y, acc[j][1]);
            acc[j][2] = fmaf(a[j], b0.z, acc[j][2]);
            acc[j][3] = fmaf(a[j], b0.w, acc[j][3]);
            acc[j][4] = fmaf(a[j], b1.x, acc[j][4]);
            acc[j][5] = fmaf(a[j], b1.y, acc[j][5]);
            acc[j][6] = fmaf(a[j], b1.z, acc[j][6]);
            acc[j][7] = fmaf(a[j], b1.w, acc[j][7]);
        }
    }

#pragma unroll
    for (int j = 0; j < TM; ++j) {
        int r = m0 + rg * TM + j;
        if (r < M) {
            float dv = dis[r];
            uint4 p;
            p.x = bf16_rne(acc[j][0] * dv) | (bf16_rne(acc[j][1] * dv) << 16);
            p.y = bf16_rne(acc[j][2] * dv) | (bf16_rne(acc[j][3] * dv) << 16);
            p.z = bf16_rne(acc[j][4] * dv) | (bf16_rne(acc[j][5] * dv) << 16);
            p.w = bf16_rne(acc[j][6] * dv) | (bf16_rne(acc[j][7] * dv) << 16);
            Hb[r * (BN / 8) + cg] = p;
        }
    }
}

// ====== Aggregate L1 (D=128): wave per node, 4 edges per wave-instr ======

__global__ __launch_bounds__(256) void k_agg1(
    const int* __restrict__ rowptr, const int* __restrict__ csr,
    const float* __restrict__ dis, const uint4* __restrict__ Hb4,
    const float* __restrict__ bias, float* __restrict__ AGG, int N)
{
    int n = (blockIdx.x * 256 + threadIdx.x) >> 6;
    int lane = threadIdx.x & 63;
    int slot = lane >> 4;        // 0..3
    int li   = lane & 15;        // uint4 index within row (16 * 16B = 256B)
    if (n >= N) return;
    int e = rowptr[n];
    const int s1 = rowptr[n + 1];
    const float dn = dis[n];

    float acc[8];
#pragma unroll
    for (int j = 0; j < 8; ++j) acc[j] = 0.f;

    for (; e + 16 <= s1; e += 16) {
        int i0 = csr[e + slot];
        int i1 = csr[e + 4 + slot];
        int i2 = csr[e + 8 + slot];
        int i3 = csr[e + 12 + slot];
        uint4 q0 = Hb4[(size_t)i0 * 16 + li];
        uint4 q1 = Hb4[(size_t)i1 * 16 + li];
        uint4 q2 = Hb4[(size_t)i2 * 16 + li];
        uint4 q3 = Hb4[(size_t)i3 * 16 + li];
        add8(acc, q0); add8(acc, q1); add8(acc, q2); add8(acc, q3);
    }
    for (; e + 4 <= s1; e += 4) {
        int i0 = csr[e + slot];
        uint4 q0 = Hb4[(size_t)i0 * 16 + li];
        add8(acc, q0);
    }
    {
        int rem = s1 - e;
        int idx = -1;
        if (slot < rem) idx = csr[e + slot];
        else if (slot == rem) idx = n;          // self-loop row
        if (idx >= 0) {
            uint4 q = Hb4[(size_t)idx * 16 + li];
            add8(acc, q);
        }
    }

#pragma unroll
    for (int j = 0; j < 8; ++j) {
        acc[j] += __shfl_xor(acc[j], 16, 64);
        acc[j] += __shfl_xor(acc[j], 32, 64);
    }

    if (slot < 2) {
        float4 bv = ((const float4*)bias)[li * 2 + slot];
        float4 o;
        o.x = fmaf(dn, acc[4 * slot + 0], bv.x);
        o.y = fmaf(dn, acc[4 * slot + 1], bv.y);
        o.z = fmaf(dn, acc[4 * slot + 2], bv.z);
        o.w = fmaf(dn, acc[4 * slot + 3], bv.w);
        ((float4*)AGG)[(size_t)n * 32 + li * 2 + slot] = o;
    }
}

// ====== Aggregate L2 (D=64): 8 edges per wave-instr ======

__global__ __launch_bounds__(256) void k_agg2(
    const int* __restrict__ rowptr, const int* __restrict__ csr,
    const float* __restrict__ dis, const uint4* __restrict__ Hb4,
    const float* __restrict__ bias, float* __restrict__ AGG, int N)
{
    int n = (blockIdx.x * 256 + threadIdx.x) >> 6;
    int lane = threadIdx.x & 63;
    int slot = lane >> 3;        // 0..7
    int li   = lane & 7;         // uint4 index within row (8 * 16B = 128B)
    if (n >= N) return;
    int e = rowptr[n];
    const int s1 = rowptr[n + 1];
    const float dn = dis[n];

    float acc[8];
#pragma unroll
    for (int j = 0; j < 8; ++j) acc[j] = 0.f;

    for (; e + 16 <= s1; e += 16) {
        int i0 = csr[e + slot];
        int i1 = csr[e + 8 + slot];
        uint4 q0 = Hb4[(size_t)i0 * 8 + li];
        uint4 q1 = Hb4[(size_t)i1 * 8 + li];
        add8(acc, q0); add8(acc, q1);
    }
    for (; e + 8 <= s1; e += 8) {
        int i0 = csr[e + slot];
        uint4 q0 = Hb4[(size_t)i0 * 8 + li];
        add8(acc, q0);
    }
    {
        int rem = s1 - e;
        int idx = -1;
        if (slot < rem) idx = csr[e + slot];
        else if (slot == rem) idx = n;
        if (idx >= 0) {
            uint4 q = Hb4[(size_t)idx * 8 + li];
            add8(acc, q);
        }
    }

#pragma unroll
    for (int j = 0; j < 8; ++j) {
        acc[j] += __shfl_xor(acc[j], 8, 64);
        acc[j] += __shfl_xor(acc[j], 16, 64);
        acc[j] += __shfl_xor(acc[j], 32, 64);
    }

    if (slot < 2) {
        float4 bv = ((const float4*)bias)[li * 2 + slot];
        float4 o;
        o.x = fmaf(dn, acc[4 * slot + 0], bv.x);
        o.y = fmaf(dn, acc[4 * slot + 1], bv.y);
        o.z = fmaf(dn, acc[4 * slot + 2], bv.z);
        o.w = fmaf(dn, acc[4 * slot + 3], bv.w);
        ((float4*)AGG)[(size_t)n * 16 + li * 2 + slot] = o;
    }
}

// ================= mean pool over sorted batch =================

__device__ inline int lower_bound(const int* __restrict__ b, int n, int v) {
    int lo = 0, hi = n;
    while (lo < hi) { int m = (lo + hi) >> 1; if (b[m] < v) lo = m + 1; else hi = m; }
    return lo;
}

__global__ __launch_bounds__(256) void k_pool(
    const int* __restrict__ batch, const float* __restrict__ AGG2,
    float* __restrict__ G, int n)
{
    int g = blockIdx.x;
    int start = lower_bound(batch, n, g);
    int end   = lower_bound(batch, n, g + 1);
    int tid = threadIdx.x;
    int f = tid & 63, stripe = tid >> 6;
    float acc = 0.f;
    for (int i = start + stripe; i < end; i += 4)
        acc += AGG2[(size_t)i * 64 + f];
    __shared__ float red[256];
    red[tid] = acc;
    __syncthreads();
    if (tid < 64) {
        float s = red[tid] + red[tid + 64] + red[tid + 128] + red[tid + 192];
        float c = (float)(end - start);
        G[g * 64 + tid] = s / fmaxf(c, 1.0f);
    }
}

// ================= classifier =================

__global__ __launch_bounds__(256) void k_fc(
    const float* __restrict__ G, const float* __restrict__ Wfc,
    const float* __restrict__ bfc, float* __restrict__ out, int ng)
{
    __shared__ float wl[640];
    __shared__ float bl[10];
    int tid = threadIdx.x;
    for (int i = tid; i < 640; i += 256) wl[i] = Wfc[i];
    if (tid < 10) bl[tid] = bfc[tid];
    __syncthreads();
    if (tid >= ng) return;
    float acc[10];
#pragma unroll
    for (int c = 0; c < 10; ++c) acc[c] = bl[c];
    for (int k = 0; k < 64; ++k) {
        float gv = G[tid * 64 + k];
#pragma unroll
        for (int c = 0; c < 10; ++c) acc[c] = fmaf(gv, wl[k * 10 + c], acc[c]);
    }
#pragma unroll
    for (int c = 0; c < 10; ++c) out[tid * 10 + c] = acc[c];
}

// ================= launch =================

extern "C" void kernel_launch(void* const* d_in, const int* in_sizes, int n_in,
                              void* d_out, int out_size, void* d_ws, size_t ws_size,
                              hipStream_t stream)
{
    const float* x    = (const float*)d_in[0];
    const int*   ei   = (const int*)d_in[1];
    const int*   batch= (const int*)d_in[2];
    const float* W1   = (const float*)d_in[3];
    const float* b1   = (const float*)d_in[4];
    const float* W2   = (const float*)d_in[5];
    const float* b2   = (const float*)d_in[6];
    const float* Wfc  = (const float*)d_in[7];
    const float* bfc  = (const float*)d_in[8];
    float* out = (float*)d_out;

    const int N  = in_sizes[0] / 128;     // 100000
    const int E  = in_sizes[1] / 2;       // 3200000
    const int ng = out_size / 10;         // 256

    const int NBK = (N + BKW - 1) / BKW;  // 391 buckets

    // ---- workspace layout (words) ----
    int*   rowptr    = (int*)d_ws;                          // 102400 (N+1)
    int*   bucketCur = rowptr + 102400;                     // 512
    float* dis       = (float*)(bucketCur + 512);           // 102400
    int*   csr       = (int*)(dis + 102400);                // E
    // region A (6.4M words): tmp (NBK*CAP=3.60M) -> Hb1 (N*64) -> agg2 (N*64)
    u32*   tmp       = (u32*)(csr + E);
    u32*   Hb1       = tmp;
    float* agg2      = (float*)tmp;
    float* agg1      = (float*)((int*)tmp + (size_t)N * 64);    // N*128
    u16*   Hb2       = (u16*)(agg1 + (size_t)N * 128);          // N*64 u16
    float* g         = (float*)((int*)Hb2 + (size_t)N * 32);    // ng*64

    // ---- CSR build: radix partition ----
    hipMemsetAsync(bucketCur, 0, NBK * sizeof(int), stream);
    k_part1<<<(E + TILE1 - 1) / TILE1, 512, 0, stream>>>(ei, bucketCur, tmp, E, N, NBK);
    k_part2<<<NBK, 512, 0, stream>>>(bucketCur, tmp, csr, rowptr, dis, N, NBK);

    // ---- layer 1 ----
    k_gemm<64, 128, 4, false><<<(N + 63) / 64, 256, 0, stream>>>(x, W1, dis, (uint4*)Hb1, N);
    k_agg1<<<(N + 3) / 4, 256, 0, stream>>>(rowptr, csr, dis, (const uint4*)Hb1, b1, agg1, N);

    // ---- layer 2 ----
    k_gemm<64, 64, 2, true><<<(N + 63) / 64, 256, 0, stream>>>(agg1, W2, dis, (uint4*)Hb2, N);
    k_agg2<<<(N + 3) / 4, 256, 0, stream>>>(rowptr, csr, dis, (const uint4*)Hb2, b2, agg2, N);

    // ---- pool + classifier ----
    k_pool<<<ng, 256, 0, stream>>>(batch, agg2, g, N);
    k_fc<<<1, 256, 0, stream>>>(g, Wfc, bfc, out, ng);
}

// Round 11
// 492.029 us; speedup vs baseline: 2.4560x; 1.0057x over previous
//
#include <hip/hip_runtime.h>
#include <math.h>

typedef unsigned int  u32;
typedef unsigned short u16;

#define TILE1 8192      // edges per pass-1 block (16/thread @ 512 threads)
#define BKW   256       // nodes per bucket (shift 8)
#define CAP   9216      // tmp slots per bucket (mean 8192, +11 sigma)

__device__ inline u32 bf16_rne(float f) {
    u32 u = __float_as_uint(f);
    return (u + 0x7FFFu + ((u >> 16) & 1u)) >> 16;
}
__device__ inline float bf_lo(u32 u) { return __uint_as_float(u << 16); }
__device__ inline float bf_hi(u32 u) { return __uint_as_float(u & 0xFFFF0000u); }

__device__ inline void add8(float* acc, uint4 q) {
    acc[0] += bf_lo(q.x); acc[1] += bf_hi(q.x);
    acc[2] += bf_lo(q.y); acc[3] += bf_hi(q.y);
    acc[4] += bf_lo(q.z); acc[5] += bf_hi(q.z);
    acc[6] += bf_lo(q.w); acc[7] += bf_hi(q.w);
}

// ================= CSR build: 2-pass radix partition =================
// pass 1: partition edges into buckets of 256 dst nodes.
// packed value = (dstLocal<<17) | src   (src < 2^17, dstLocal < 256)
// count-histogram replicated x2 (lane parity) to halve LDS-atomic contention.

__global__ __launch_bounds__(512) void k_part1(const int* __restrict__ ei,
                                               int* __restrict__ bucketCur,
                                               u32* __restrict__ tmp,
                                               int E, int N, int NBK) {
    __shared__ int hist[1024];    // two replicas for count; [0:512) reused as cursor
    __shared__ int base[512];
    const int tid = threadIdx.x;
    if (tid < NBK) { hist[tid] = 0; hist[512 + tid] = 0; }
    __syncthreads();

    const int rep = (tid & 1) << 9;
    const int t0 = blockIdx.x * TILE1;
    int sv[16], dv[16], key[16];
#pragma unroll
    for (int j = 0; j < 16; ++j) {
        int i = t0 + j * 512 + tid;
        key[j] = -1;
        if (i < E) {
            sv[j] = ei[i];
            dv[j] = ei[E + i];
            if ((unsigned)dv[j] < (unsigned)N && (unsigned)sv[j] < (unsigned)N) {
                key[j] = dv[j] >> 8;
                atomicAdd(&hist[key[j] + rep], 1);
            }
        }
    }
    __syncthreads();
    if (tid < NBK) {
        int tot = hist[tid] + hist[512 + tid];
        base[tid] = atomicAdd(&bucketCur[tid], tot);
        hist[tid] = 0;                 // running cursor for placement
    }
    __syncthreads();
#pragma unroll
    for (int j = 0; j < 16; ++j) {
        if (key[j] >= 0) {
            int slot = atomicAdd(&hist[key[j]], 1);
            int off = base[key[j]] + slot;
            if (off < CAP)
                tmp[(size_t)key[j] * CAP + off] =
                    ((u32)(dv[j] & 255) << 17) | (u32)sv[j];
        }
    }
}

// pass 2: one block per bucket. inline scan of bucket counts, 256-entry
// histogram -> rowptr + dis, then place csr with LDS cursors.
__global__ __launch_bounds__(512) void k_part2(const int* __restrict__ bucketCnt,
                                               const u32* __restrict__ tmp,
                                               int* __restrict__ csr,
                                               int* __restrict__ rowptr,
                                               float* __restrict__ dis,
                                               int N, int NBK) {
    __shared__ int hist[256];
    __shared__ int ts[512];
    __shared__ int sStart;
    const int b = blockIdx.x;
    const int t = threadIdx.x;

    // exclusive scan of bucketCnt (NBK <= 512) to get this bucket's start
    int myCnt = (t < NBK) ? bucketCnt[t] : 0;
    ts[t] = myCnt;
    __syncthreads();
    for (int off = 1; off < 512; off <<= 1) {
        int u = (t >= off) ? ts[t - off] : 0;
        __syncthreads();
        ts[t] += u;
        __syncthreads();
    }
    if (t == b) sStart = ts[t] - myCnt;
    if (b == 0 && t == NBK - 1) rowptr[N] = ts[t];
    __syncthreads();
    const int start = sStart;
    const int cnt = bucketCnt[b];
    const u32* src = tmp + (size_t)b * CAP;

    if (t < 256) hist[t] = 0;
    __syncthreads();
    for (int i = t; i < cnt; i += 512)
        atomicAdd(&hist[src[i] >> 17], 1);
    __syncthreads();

    // exclusive scan of hist[0..255] (all threads hit barriers)
    int h = (t < 256) ? hist[t] : 0;
    ts[t] = h;
    __syncthreads();
    for (int off = 1; off < 512; off <<= 1) {
        int u = (t >= off) ? ts[t - off] : 0;
        __syncthreads();
        ts[t] += u;
        __syncthreads();
    }
    if (t < 256) hist[t] = ts[t] - h;       // exclusive
    __syncthreads();

    // rowptr + dis for this bucket's nodes
    if (t < 256) {
        int gn = (b << 8) + t;
        if (gn < N) {
            int e0 = hist[t];
            int e1 = (t < 255) ? hist[t + 1] : cnt;
            rowptr[gn] = start + e0;
            dis[gn] = rsqrtf((float)(e1 - e0) + 1.0f);
        }
    }
    __syncthreads();

    // place (hist becomes running cursor)
    for (int i = t; i < cnt; i += 512) {
        u32 v = src[i];
        int p = atomicAdd(&hist[v >> 17], 1);
        csr[start + p] = (int)(v & 0x1FFFFu);
    }
}

// ========== GEMM L1 (fp32 X): Hb = bf16( (X @ W) * dis[row] ) ==========

template <int BM, int BN, int TM>
__global__ __launch_bounds__(256) void k_gemm(
    const float* __restrict__ X, const float* __restrict__ W,
    const float* __restrict__ dis, uint4* __restrict__ Hb, int M)
{
    constexpr int K = 128;
    constexpr int TN = 8;
    constexpr int RG = BM / TM;
    constexpr int LSTR = BM + 4;
    __shared__ float xs[K * LSTR];

    const int tid = threadIdx.x;
    const int m0 = blockIdx.x * BM;

    const float4* X4 = (const float4*)X;
    constexpr int NV = BM * (K / 4) / 256;
#pragma unroll
    for (int i = 0; i < NV; ++i) {
        int idx = tid + i * 256;
        int r = idx >> 5;
        int kq = idx & 31;
        float4 v = make_float4(0.f, 0.f, 0.f, 0.f);
        int gr = m0 + r;
        if (gr < M) v = X4[gr * 32 + kq];
        int kb = kq * 4;
        xs[(kb + 0) * LSTR + r] = v.x;
        xs[(kb + 1) * LSTR + r] = v.y;
        xs[(kb + 2) * LSTR + r] = v.z;
        xs[(kb + 3) * LSTR + r] = v.w;
    }
    __syncthreads();

    const int rg = tid % RG;
    const int cg = tid / RG;

    float acc[TM][TN];
#pragma unroll
    for (int j = 0; j < TM; ++j)
#pragma unroll
        for (int c = 0; c < TN; ++c) acc[j][c] = 0.f;

    const float4* W4 = (const float4*)W;
#pragma unroll 4
    for (int k = 0; k < K; ++k) {
        float a[TM];
        if constexpr (TM == 4) {
            float4 av = *(const float4*)&xs[k * LSTR + rg * 4];
            a[0] = av.x; a[1] = av.y; a[2] = av.z; a[3] = av.w;
        } else {
            float2 av = *(const float2*)&xs[k * LSTR + rg * 2];
            a[0] = av.x; a[1] = av.y;
        }
        float4 b0 = W4[k * (BN / 4) + cg * 2];
        float4 b1 = W4[k * (BN / 4) + cg * 2 + 1];
#pragma unroll
        for (int j = 0; j < TM; ++j) {
            acc[j][0] = fmaf(a[j], b0.x, acc[j][0]);
            acc[j][1] = fmaf(a[j], b0.y, acc[j][1]);
            acc[j][2] = fmaf(a[j], b0.z, acc[j][2]);
            acc[j][3] = fmaf(a[j], b0.w, acc[j][3]);
            acc[j][4] = fmaf(a[j], b1.x, acc[j][4]);
            acc[j][5] = fmaf(a[j], b1.y, acc[j][5]);
            acc[j][6] = fmaf(a[j], b1.z, acc[j][6]);
            acc[j][7] = fmaf(a[j], b1.w, acc[j][7]);
        }
    }

#pragma unroll
    for (int j = 0; j < TM; ++j) {
        int r = m0 + rg * TM + j;
        if (r < M) {
            float dv = dis[r];
            uint4 p;
            p.x = bf16_rne(acc[j][0] * dv) | (bf16_rne(acc[j][1] * dv) << 16);
            p.y = bf16_rne(acc[j][2] * dv) | (bf16_rne(acc[j][3] * dv) << 16);
            p.z = bf16_rne(acc[j][4] * dv) | (bf16_rne(acc[j][5] * dv) << 16);
            p.w = bf16_rne(acc[j][6] * dv) | (bf16_rne(acc[j][7] * dv) << 16);
            Hb[r * (BN / 8) + cg] = p;
        }
    }
}

// ========== GEMM L2 (packed-bf16 X, relu at load): Hb2 = bf16((relu(X)@W)*dis) ==========
// BM=64, BN=64, TM=2. X row = 128 bf16 = 64 u32 = 16 uint4.
// Flat u32 layout: u32 index k holds cols 2k,2k+1 -> uint4 kq covers k-range
// [8*kq, 8*kq+8).

__global__ __launch_bounds__(256) void k_gemm2b(
    const u32* __restrict__ Xb, const float* __restrict__ W,
    const float* __restrict__ dis, uint4* __restrict__ Hb, int M)
{
    constexpr int K = 128;
    constexpr int BM = 64, BN = 64, TM = 2, TN = 8;
    constexpr int RG = BM / TM;
    constexpr int LSTR = BM + 4;
    __shared__ float xs[K * LSTR];

    const int tid = threadIdx.x;
    const int m0 = blockIdx.x * BM;

    const uint4* X4 = (const uint4*)Xb;          // 16 uint4 per row (64 u32)
#pragma unroll
    for (int i = 0; i < 4; ++i) {                // 64 rows * 16 uint4 / 256 thr
        int idx = tid + i * 256;
        int r = idx >> 4;
        int kq = idx & 15;
        uint4 q = make_uint4(0u, 0u, 0u, 0u);
        int gr = m0 + r;
        if (gr < M) q = X4[(size_t)gr * 16 + kq];
        int kb = kq * 8;                         // 8 k-entries per uint4
        xs[(kb + 0) * LSTR + r] = fmaxf(bf_lo(q.x), 0.f);
        xs[(kb + 1) * LSTR + r] = fmaxf(bf_hi(q.x), 0.f);
        xs[(kb + 2) * LSTR + r] = fmaxf(bf_lo(q.y), 0.f);
        xs[(kb + 3) * LSTR + r] = fmaxf(bf_hi(q.y), 0.f);
        xs[(kb + 4) * LSTR + r] = fmaxf(bf_lo(q.z), 0.f);
        xs[(kb + 5) * LSTR + r] = fmaxf(bf_hi(q.z), 0.f);
        xs[(kb + 6) * LSTR + r] = fmaxf(bf_lo(q.w), 0.f);
        xs[(kb + 7) * LSTR + r] = fmaxf(bf_hi(q.w), 0.f);
    }
    __syncthreads();

    const int rg = tid % RG;
    const int cg = tid / RG;

    float acc[TM][TN];
#pragma unroll
    for (int j = 0; j < TM; ++j)
#pragma unroll
        for (int c = 0; c < TN; ++c) acc[j][c] = 0.f;

    const float4* W4 = (const float4*)W;
#pragma unroll 4
    for (int k = 0; k < K; ++k) {
        float2 av = *(const float2*)&xs[k * LSTR + rg * 2];
        float a0 = av.x, a1 = av.y;
        float4 b0 = W4[k * (BN / 4) + cg * 2];
        float4 b1 = W4[k * (BN / 4) + cg * 2 + 1];
        acc[0][0] = fmaf(a0, b0.x, acc[0][0]); acc[0][1] = fmaf(a0, b0.y, acc[0][1]);
        acc[0][2] = fmaf(a0, b0.z, acc[0][2]); acc[0][3] = fmaf(a0, b0.w, acc[0][3]);
        acc[0][4] = fmaf(a0, b1.x, acc[0][4]); acc[0][5] = fmaf(a0, b1.y, acc[0][5]);
        acc[0][6] = fmaf(a0, b1.z, acc[0][6]); acc[0][7] = fmaf(a0, b1.w, acc[0][7]);
        acc[1][0] = fmaf(a1, b0.x, acc[1][0]); acc[1][1] = fmaf(a1, b0.y, acc[1][1]);
        acc[1][2] = fmaf(a1, b0.z, acc[1][2]); acc[1][3] = fmaf(a1, b0.w, acc[1][3]);
        acc[1][4] = fmaf(a1, b1.x, acc[1][4]); acc[1][5] = fmaf(a1, b1.y, acc[1][5]);
        acc[1][6] = fmaf(a1, b1.z, acc[1][6]); acc[1][7] = fmaf(a1, b1.w, acc[1][7]);
    }

#pragma unroll
    for (int j = 0; j < TM; ++j) {
        int r = m0 + rg * TM + j;
        if (r < M) {
            float dv = dis[r];
            uint4 p;
            p.x = bf16_rne(acc[j][0] * dv) | (bf16_rne(acc[j][1] * dv) << 16);
            p.y = bf16_rne(acc[j][2] * dv) | (bf16_rne(acc[j][3] * dv) << 16);
            p.z = bf16_rne(acc[j][4] * dv) | (bf16_rne(acc[j][5] * dv) << 16);
            p.w = bf16_rne(acc[j][6] * dv) | (bf16_rne(acc[j][7] * dv) << 16);
            Hb[r * (BN / 8) + cg] = p;
        }
    }
}

// ====== Aggregate L1 (D=128): wave per node, 4 edges per wave-instr.
// Output: packed bf16 (feeds gemm2b). ======

__global__ __launch_bounds__(256) void k_agg1(
    const int* __restrict__ rowptr, const int* __restrict__ csr,
    const float* __restrict__ dis, const uint4* __restrict__ Hb4,
    const float* __restrict__ bias, u32* __restrict__ AGGb, int N)
{
    int n = (blockIdx.x * 256 + threadIdx.x) >> 6;
    int lane = threadIdx.x & 63;
    int slot = lane >> 4;        // 0..3
    int li   = lane & 15;        // uint4 index within row (16 * 16B = 256B)
    if (n >= N) return;
    int e = rowptr[n];
    const int s1 = rowptr[n + 1];
    const float dn = dis[n];

    float acc[8];
#pragma unroll
    for (int j = 0; j < 8; ++j) acc[j] = 0.f;

    for (; e + 16 <= s1; e += 16) {
        int i0 = csr[e + slot];
        int i1 = csr[e + 4 + slot];
        int i2 = csr[e + 8 + slot];
        int i3 = csr[e + 12 + slot];
        uint4 q0 = Hb4[(size_t)i0 * 16 + li];
        uint4 q1 = Hb4[(size_t)i1 * 16 + li];
        uint4 q2 = Hb4[(size_t)i2 * 16 + li];
        uint4 q3 = Hb4[(size_t)i3 * 16 + li];
        add8(acc, q0); add8(acc, q1); add8(acc, q2); add8(acc, q3);
    }
    for (; e + 4 <= s1; e += 4) {
        int i0 = csr[e + slot];
        uint4 q0 = Hb4[(size_t)i0 * 16 + li];
        add8(acc, q0);
    }
    {
        int rem = s1 - e;
        int idx = -1;
        if (slot < rem) idx = csr[e + slot];
        else if (slot == rem) idx = n;          // self-loop row
        if (idx >= 0) {
            uint4 q = Hb4[(size_t)idx * 16 + li];
            add8(acc, q);
        }
    }

#pragma unroll
    for (int j = 0; j < 8; ++j) {
        acc[j] += __shfl_xor(acc[j], 16, 64);
        acc[j] += __shfl_xor(acc[j], 32, 64);
    }

    // slot s holds cols [8li+4s, 8li+4s+4); pack 4 fp32 -> 2 u32 (bf16x2)
    if (slot < 2) {
        float4 bv = ((const float4*)bias)[li * 2 + slot];
        float o0 = fmaf(dn, acc[4 * slot + 0], bv.x);
        float o1 = fmaf(dn, acc[4 * slot + 1], bv.y);
        float o2 = fmaf(dn, acc[4 * slot + 2], bv.z);
        float o3 = fmaf(dn, acc[4 * slot + 3], bv.w);
        uint2 p;
        p.x = bf16_rne(o0) | (bf16_rne(o1) << 16);
        p.y = bf16_rne(o2) | (bf16_rne(o3) << 16);
        ((uint2*)AGGb)[(size_t)n * 32 + li * 2 + slot] = p;
    }
}

// ====== Aggregate L2 (D=64): 8 edges per wave-instr; fp32 output (pool input) ======

__global__ __launch_bounds__(256) void k_agg2(
    const int* __restrict__ rowptr, const int* __restrict__ csr,
    const float* __restrict__ dis, const uint4* __restrict__ Hb4,
    const float* __restrict__ bias, float* __restrict__ AGG, int N)
{
    int n = (blockIdx.x * 256 + threadIdx.x) >> 6;
    int lane = threadIdx.x & 63;
    int slot = lane >> 3;        // 0..7
    int li   = lane & 7;         // uint4 index within row (8 * 16B = 128B)
    if (n >= N) return;
    int e = rowptr[n];
    const int s1 = rowptr[n + 1];
    const float dn = dis[n];

    float acc[8];
#pragma unroll
    for (int j = 0; j < 8; ++j) acc[j] = 0.f;

    for (; e + 16 <= s1; e += 16) {
        int i0 = csr[e + slot];
        int i1 = csr[e + 8 + slot];
        uint4 q0 = Hb4[(size_t)i0 * 8 + li];
        uint4 q1 = Hb4[(size_t)i1 * 8 + li];
        add8(acc, q0); add8(acc, q1);
    }
    for (; e + 8 <= s1; e += 8) {
        int i0 = csr[e + slot];
        uint4 q0 = Hb4[(size_t)i0 * 8 + li];
        add8(acc, q0);
    }
    {
        int rem = s1 - e;
        int idx = -1;
        if (slot < rem) idx = csr[e + slot];
        else if (slot == rem) idx = n;
        if (idx >= 0) {
            uint4 q = Hb4[(size_t)idx * 8 + li];
            add8(acc, q);
        }
    }

#pragma unroll
    for (int j = 0; j < 8; ++j) {
        acc[j] += __shfl_xor(acc[j], 8, 64);
        acc[j] += __shfl_xor(acc[j], 16, 64);
        acc[j] += __shfl_xor(acc[j], 32, 64);
    }

    if (slot < 2) {
        float4 bv = ((const float4*)bias)[li * 2 + slot];
        float4 o;
        o.x = fmaf(dn, acc[4 * slot + 0], bv.x);
        o.y = fmaf(dn, acc[4 * slot + 1], bv.y);
        o.z = fmaf(dn, acc[4 * slot + 2], bv.z);
        o.w = fmaf(dn, acc[4 * slot + 3], bv.w);
        ((float4*)AGG)[(size_t)n * 16 + li * 2 + slot] = o;
    }
}

// ================= mean pool over sorted batch =================

__device__ inline int lower_bound(const int* __restrict__ b, int n, int v) {
    int lo = 0, hi = n;
    while (lo < hi) { int m = (lo + hi) >> 1; if (b[m] < v) lo = m + 1; else hi = m; }
    return lo;
}

__global__ __launch_bounds__(256) void k_pool(
    const int* __restrict__ batch, const float* __restrict__ AGG2,
    float* __restrict__ G, int n)
{
    int g = blockIdx.x;
    int start = lower_bound(batch, n, g);
    int end   = lower_bound(batch, n, g + 1);
    int tid = threadIdx.x;
    int f = tid & 63, stripe = tid >> 6;
    float acc = 0.f;
    for (int i = start + stripe; i < end; i += 4)
        acc += AGG2[(size_t)i * 64 + f];
    __shared__ float red[256];
    red[tid] = acc;
    __syncthreads();
    if (tid < 64) {
        float s = red[tid] + red[tid + 64] + red[tid + 128] + red[tid + 192];
        float c = (float)(end - start);
        G[g * 64 + tid] = s / fmaxf(c, 1.0f);
    }
}

// ================= classifier =================

__global__ __launch_bounds__(256) void k_fc(
    const float* __restrict__ G, const float* __restrict__ Wfc,
    const float* __restrict__ bfc, float* __restrict__ out, int ng)
{
    __shared__ float wl[640];
    __shared__ float bl[10];
    int tid = threadIdx.x;
    for (int i = tid; i < 640; i += 256) wl[i] = Wfc[i];
    if (tid < 10) bl[tid] = bfc[tid];
    __syncthreads();
    if (tid >= ng) return;
    float acc[10];
#pragma unroll
    for (int c = 0; c < 10; ++c) acc[c] = bl[c];
    for (int k = 0; k < 64; ++k) {
        float gv = G[tid * 64 + k];
#pragma unroll
        for (int c = 0; c < 10; ++c) acc[c] = fmaf(gv, wl[k * 10 + c], acc[c]);
    }
#pragma unroll
    for (int c = 0; c < 10; ++c) out[tid * 10 + c] = acc[c];
}

// ================= launch =================

extern "C" void kernel_launch(void* const* d_in, const int* in_sizes, int n_in,
                              void* d_out, int out_size, void* d_ws, size_t ws_size,
                              hipStream_t stream)
{
    const float* x    = (const float*)d_in[0];
    const int*   ei   = (const int*)d_in[1];
    const int*   batch= (const int*)d_in[2];
    const float* W1   = (const float*)d_in[3];
    const float* b1   = (const float*)d_in[4];
    const float* W2   = (const float*)d_in[5];
    const float* b2   = (const float*)d_in[6];
    const float* Wfc  = (const float*)d_in[7];
    const float* bfc  = (const float*)d_in[8];
    float* out = (float*)d_out;

    const int N  = in_sizes[0] / 128;     // 100000
    const int E  = in_sizes[1] / 2;       // 3200000
    const int ng = out_size / 10;         // 256

    const int NBK = (N + BKW - 1) / BKW;  // 391 buckets

    // ---- workspace layout (words) ----
    int*   rowptr    = (int*)d_ws;                          // 102400 (N+1)
    int*   bucketCur = rowptr + 102400;                     // 512
    float* dis       = (float*)(bucketCur + 512);           // 102400
    int*   csr       = (int*)(dis + 102400);                // E
    // region A (6.4M words): tmp (NBK*CAP=3.60M) -> Hb1 (N*64) -> agg2 (N*64)
    u32*   tmp       = (u32*)(csr + E);
    u32*   Hb1       = tmp;
    float* agg2      = (float*)tmp;
    u32*   agg1b     = (u32*)((int*)tmp + (size_t)N * 64);      // N*64 u32 (bf16 packed)
    u16*   Hb2       = (u16*)((int*)agg1b + (size_t)N * 128);   // N*64 u16
    float* g         = (float*)((int*)Hb2 + (size_t)N * 32);    // ng*64

    // ---- CSR build: radix partition ----
    hipMemsetAsync(bucketCur, 0, NBK * sizeof(int), stream);
    k_part1<<<(E + TILE1 - 1) / TILE1, 512, 0, stream>>>(ei, bucketCur, tmp, E, N, NBK);
    k_part2<<<NBK, 512, 0, stream>>>(bucketCur, tmp, csr, rowptr, dis, N, NBK);

    // ---- layer 1 ----
    k_gemm<64, 128, 4><<<(N + 63) / 64, 256, 0, stream>>>(x, W1, dis, (uint4*)Hb1, N);
    k_agg1<<<(N + 3) / 4, 256, 0, stream>>>(rowptr, csr, dis, (const uint4*)Hb1, b1, agg1b, N);

    // ---- layer 2 ----
    k_gemm2b<<<(N + 63) / 64, 256, 0, stream>>>(agg1b, W2, dis, (uint4*)Hb2, N);
    k_agg2<<<(N + 3) / 4, 256, 0, stream>>>(rowptr, csr, dis, (const uint4*)Hb2, b2, agg2, N);

    // ---- pool + classifier ----
    k_pool<<<ng, 256, 0, stream>>>(batch, agg2, g, N);
    k_fc<<<1, 256, 0, stream>>>(g, Wfc, bfc, out, ng);
}

// Round 12
// 453.002 us; speedup vs baseline: 2.6675x; 1.0862x over previous
//
#include <hip/hip_runtime.h>
#include <math.h>

typedef unsigned int  u32;
typedef unsigned short u16;

#define TILE1 8192      // edges per pass-1 block (16/thread @ 512 threads)
#define BKW   256       // nodes per bucket (shift 8)
#define CAP   9216      // tmp slots per bucket (mean 8192, +11 sigma)

typedef __attribute__((ext_vector_type(8))) short bf16x8;
typedef __attribute__((ext_vector_type(4))) float f32x4;
union frag_u { bf16x8 v; u32 u[4]; uint4 q; };

__device__ inline u32 bf16_rne(float f) {
    u32 u = __float_as_uint(f);
    return (u + 0x7FFFu + ((u >> 16) & 1u)) >> 16;
}
__device__ inline float bf_lo(u32 u) { return __uint_as_float(u << 16); }
__device__ inline float bf_hi(u32 u) { return __uint_as_float(u & 0xFFFF0000u); }

__device__ inline void add8(float* acc, uint4 q) {
    acc[0] += bf_lo(q.x); acc[1] += bf_hi(q.x);
    acc[2] += bf_lo(q.y); acc[3] += bf_hi(q.y);
    acc[4] += bf_lo(q.z); acc[5] += bf_hi(q.z);
    acc[6] += bf_lo(q.w); acc[7] += bf_hi(q.w);
}

// relu on packed bf16x2: clear halves whose sign bit is set
__device__ inline u32 relu_pk(u32 v) {
    u32 s = v & 0x80008000u;
    u32 m = (s >> 15) * 0xFFFFu;
    return v & ~m;
}

// ================= CSR build: 2-pass radix partition =================

__global__ __launch_bounds__(512) void k_part1(const int* __restrict__ ei,
                                               int* __restrict__ bucketCur,
                                               u32* __restrict__ tmp,
                                               int E, int N, int NBK) {
    __shared__ int hist[1024];    // two replicas for count; [0:512) reused as cursor
    __shared__ int base[512];
    const int tid = threadIdx.x;
    if (tid < NBK) { hist[tid] = 0; hist[512 + tid] = 0; }
    __syncthreads();

    const int rep = (tid & 1) << 9;
    const int t0 = blockIdx.x * TILE1;
    int sv[16], dv[16], key[16];
#pragma unroll
    for (int j = 0; j < 16; ++j) {
        int i = t0 + j * 512 + tid;
        key[j] = -1;
        if (i < E) {
            sv[j] = ei[i];
            dv[j] = ei[E + i];
            if ((unsigned)dv[j] < (unsigned)N && (unsigned)sv[j] < (unsigned)N) {
                key[j] = dv[j] >> 8;
                atomicAdd(&hist[key[j] + rep], 1);
            }
        }
    }
    __syncthreads();
    if (tid < NBK) {
        int tot = hist[tid] + hist[512 + tid];
        base[tid] = atomicAdd(&bucketCur[tid], tot);
        hist[tid] = 0;                 // running cursor for placement
    }
    __syncthreads();
#pragma unroll
    for (int j = 0; j < 16; ++j) {
        if (key[j] >= 0) {
            int slot = atomicAdd(&hist[key[j]], 1);
            int off = base[key[j]] + slot;
            if (off < CAP)
                tmp[(size_t)key[j] * CAP + off] =
                    ((u32)(dv[j] & 255) << 17) | (u32)sv[j];
        }
    }
}

__global__ __launch_bounds__(512) void k_part2(const int* __restrict__ bucketCnt,
                                               const u32* __restrict__ tmp,
                                               int* __restrict__ csr,
                                               int* __restrict__ rowptr,
                                               float* __restrict__ dis,
                                               int N, int NBK) {
    __shared__ int hist[256];
    __shared__ int ts[512];
    __shared__ int sStart;
    const int b = blockIdx.x;
    const int t = threadIdx.x;

    int myCnt = (t < NBK) ? bucketCnt[t] : 0;
    ts[t] = myCnt;
    __syncthreads();
    for (int off = 1; off < 512; off <<= 1) {
        int u = (t >= off) ? ts[t - off] : 0;
        __syncthreads();
        ts[t] += u;
        __syncthreads();
    }
    if (t == b) sStart = ts[t] - myCnt;
    if (b == 0 && t == NBK - 1) rowptr[N] = ts[t];
    __syncthreads();
    const int start = sStart;
    const int cnt = bucketCnt[b];
    const u32* src = tmp + (size_t)b * CAP;

    if (t < 256) hist[t] = 0;
    __syncthreads();
    for (int i = t; i < cnt; i += 512)
        atomicAdd(&hist[src[i] >> 17], 1);
    __syncthreads();

    int h = (t < 256) ? hist[t] : 0;
    ts[t] = h;
    __syncthreads();
    for (int off = 1; off < 512; off <<= 1) {
        int u = (t >= off) ? ts[t - off] : 0;
        __syncthreads();
        ts[t] += u;
        __syncthreads();
    }
    if (t < 256) hist[t] = ts[t] - h;       // exclusive
    __syncthreads();

    if (t < 256) {
        int gn = (b << 8) + t;
        if (gn < N) {
            int e0 = hist[t];
            int e1 = (t < 255) ? hist[t + 1] : cnt;
            rowptr[gn] = start + e0;
            dis[gn] = rsqrtf((float)(e1 - e0) + 1.0f);
        }
    }
    __syncthreads();

    for (int i = t; i < cnt; i += 512) {
        u32 v = src[i];
        int p = atomicAdd(&hist[v >> 17], 1);
        csr[start + p] = (int)(v & 0x1FFFFu);
    }
}

// ========== weight convert: n-major bf16 hi/lo tables ==========
// Wf1[n][k] (128x128), Wf2[n][k] (64x128); packed 2 k per u32.

__global__ __launch_bounds__(256) void k_convW(
    const float* __restrict__ W1, const float* __restrict__ W2,
    u32* __restrict__ W1h, u32* __restrict__ W1l,
    u32* __restrict__ W2h, u32* __restrict__ W2l)
{
    int idx = blockIdx.x * 256 + threadIdx.x;
    if (idx < 8192) {
        int n = idx >> 6, k = (idx & 63) * 2;
        float w0 = W1[k * 128 + n], w1 = W1[(k + 1) * 128 + n];
        u32 h0 = bf16_rne(w0), h1 = bf16_rne(w1);
        u32 l0 = bf16_rne(w0 - __uint_as_float(h0 << 16));
        u32 l1 = bf16_rne(w1 - __uint_as_float(h1 << 16));
        W1h[idx] = h0 | (h1 << 16);
        W1l[idx] = l0 | (l1 << 16);
    } else if (idx < 12288) {
        int i2 = idx - 8192;
        int n = i2 >> 6, k = (i2 & 63) * 2;
        float w0 = W2[k * 64 + n], w1 = W2[(k + 1) * 64 + n];
        u32 h0 = bf16_rne(w0), h1 = bf16_rne(w1);
        u32 l0 = bf16_rne(w0 - __uint_as_float(h0 << 16));
        u32 l1 = bf16_rne(w1 - __uint_as_float(h1 << 16));
        W2h[i2] = h0 | (h1 << 16);
        W2l[i2] = l0 | (l1 << 16);
    }
}

// ========== GEMM1 (MFMA): Hb1 = bf16( (X @ W1) * dis ), X fp32 hi/lo split ==========
// Wave computes 16 rows x 128 cols. A[m=lane&15][k=quad*8+j]; C col=lane&15,row=quad*4+r.

__global__ __launch_bounds__(256) void k_gemm1m(
    const float* __restrict__ X, const u32* __restrict__ Wh,
    const u32* __restrict__ Wl, const float* __restrict__ dis,
    u32* __restrict__ Hb, int M)
{
    const int w = threadIdx.x >> 6, lane = threadIdx.x & 63;
    const int mrow = blockIdx.x * 64 + w * 16;
    if (mrow >= M) return;
    const int m16 = lane & 15, quad = lane >> 4;
    int gm = mrow + m16; if (gm >= M) gm = M - 1;

    frag_u Ah[4], Al[4];
    const float* xr = X + (size_t)gm * 128;
#pragma unroll
    for (int kt = 0; kt < 4; ++kt) {
        int kb = kt * 32 + quad * 8;
        float4 xa = *(const float4*)(xr + kb);
        float4 xb = *(const float4*)(xr + kb + 4);
        float xe[8] = {xa.x, xa.y, xa.z, xa.w, xb.x, xb.y, xb.z, xb.w};
#pragma unroll
        for (int j = 0; j < 4; ++j) {
            u32 h0 = bf16_rne(xe[2 * j]),     h1 = bf16_rne(xe[2 * j + 1]);
            u32 l0 = bf16_rne(xe[2 * j]     - __uint_as_float(h0 << 16));
            u32 l1 = bf16_rne(xe[2 * j + 1] - __uint_as_float(h1 << 16));
            Ah[kt].u[j] = h0 | (h1 << 16);
            Al[kt].u[j] = l0 | (l1 << 16);
        }
    }

    float dv[4];
#pragma unroll
    for (int r = 0; r < 4; ++r) {
        int gR = mrow + quad * 4 + r;
        dv[r] = (gR < M) ? dis[gR] : 0.f;
    }

    const uint4* Wh4 = (const uint4*)Wh;
    const uint4* Wl4 = (const uint4*)Wl;
#pragma unroll
    for (int nt = 0; nt < 8; ++nt) {
        f32x4 acc = {0.f, 0.f, 0.f, 0.f};
        int nrow = nt * 16 + m16;
#pragma unroll
        for (int kt = 0; kt < 4; ++kt) {
            frag_u Bh, Bl;
            Bh.q = Wh4[nrow * 16 + kt * 4 + quad];
            Bl.q = Wl4[nrow * 16 + kt * 4 + quad];
            acc = __builtin_amdgcn_mfma_f32_16x16x32_bf16(Al[kt].v, Bh.v, acc, 0, 0, 0);
            acc = __builtin_amdgcn_mfma_f32_16x16x32_bf16(Ah[kt].v, Bl.v, acc, 0, 0, 0);
            acc = __builtin_amdgcn_mfma_f32_16x16x32_bf16(Ah[kt].v, Bh.v, acc, 0, 0, 0);
        }
#pragma unroll
        for (int r = 0; r < 4; ++r) {
            float vs = acc[r] * dv[r];
            float vo = __shfl_xor(vs, 1, 64);
            if ((m16 & 1) == 0) {
                int gR = mrow + quad * 4 + r;
                if (gR < M)
                    Hb[(size_t)gR * 64 + nt * 8 + (m16 >> 1)] =
                        bf16_rne(vs) | (bf16_rne(vo) << 16);
            }
        }
    }
}

// ========== GEMM2 (MFMA): Hb2 = bf16( (relu(agg1b) @ W2) * dis ) ==========
// A = bf16 rows direct from global (exact), W2 hi/lo split.

__global__ __launch_bounds__(256) void k_gemm2m(
    const u32* __restrict__ Xb, const u32* __restrict__ Wh,
    const u32* __restrict__ Wl, const float* __restrict__ dis,
    u32* __restrict__ Hb, int M)
{
    const int w = threadIdx.x >> 6, lane = threadIdx.x & 63;
    const int mrow = blockIdx.x * 64 + w * 16;
    if (mrow >= M) return;
    const int m16 = lane & 15, quad = lane >> 4;
    int gm = mrow + m16; if (gm >= M) gm = M - 1;

    const uint4* X4 = (const uint4*)Xb;
    frag_u A[4];
#pragma unroll
    for (int kt = 0; kt < 4; ++kt) {
        A[kt].q = X4[(size_t)gm * 16 + kt * 4 + quad];
#pragma unroll
        for (int j = 0; j < 4; ++j) A[kt].u[j] = relu_pk(A[kt].u[j]);
    }

    float dv[4];
#pragma unroll
    for (int r = 0; r < 4; ++r) {
        int gR = mrow + quad * 4 + r;
        dv[r] = (gR < M) ? dis[gR] : 0.f;
    }

    const uint4* Wh4 = (const uint4*)Wh;
    const uint4* Wl4 = (const uint4*)Wl;
#pragma unroll
    for (int nt = 0; nt < 4; ++nt) {
        f32x4 acc = {0.f, 0.f, 0.f, 0.f};
        int nrow = nt * 16 + m16;
#pragma unroll
        for (int kt = 0; kt < 4; ++kt) {
            frag_u Bh, Bl;
            Bh.q = Wh4[nrow * 16 + kt * 4 + quad];
            Bl.q = Wl4[nrow * 16 + kt * 4 + quad];
            acc = __builtin_amdgcn_mfma_f32_16x16x32_bf16(A[kt].v, Bl.v, acc, 0, 0, 0);
            acc = __builtin_amdgcn_mfma_f32_16x16x32_bf16(A[kt].v, Bh.v, acc, 0, 0, 0);
        }
#pragma unroll
        for (int r = 0; r < 4; ++r) {
            float vs = acc[r] * dv[r];
            float vo = __shfl_xor(vs, 1, 64);
            if ((m16 & 1) == 0) {
                int gR = mrow + quad * 4 + r;
                if (gR < M)
                    Hb[(size_t)gR * 32 + nt * 8 + (m16 >> 1)] =
                        bf16_rne(vs) | (bf16_rne(vo) << 16);
            }
        }
    }
}

// ====== Aggregate L1 (D=128): wave per node, 4 edges per wave-instr.
// Output: packed bf16 (feeds gemm2m). ======

__global__ __launch_bounds__(256) void k_agg1(
    const int* __restrict__ rowptr, const int* __restrict__ csr,
    const float* __restrict__ dis, const uint4* __restrict__ Hb4,
    const float* __restrict__ bias, u32* __restrict__ AGGb, int N)
{
    int n = (blockIdx.x * 256 + threadIdx.x) >> 6;
    int lane = threadIdx.x & 63;
    int slot = lane >> 4;        // 0..3
    int li   = lane & 15;        // uint4 index within row (16 * 16B = 256B)
    if (n >= N) return;
    int e = rowptr[n];
    const int s1 = rowptr[n + 1];
    const float dn = dis[n];

    float acc[8];
#pragma unroll
    for (int j = 0; j < 8; ++j) acc[j] = 0.f;

    for (; e + 16 <= s1; e += 16) {
        int i0 = csr[e + slot];
        int i1 = csr[e + 4 + slot];
        int i2 = csr[e + 8 + slot];
        int i3 = csr[e + 12 + slot];
        uint4 q0 = Hb4[(size_t)i0 * 16 + li];
        uint4 q1 = Hb4[(size_t)i1 * 16 + li];
        uint4 q2 = Hb4[(size_t)i2 * 16 + li];
        uint4 q3 = Hb4[(size_t)i3 * 16 + li];
        add8(acc, q0); add8(acc, q1); add8(acc, q2); add8(acc, q3);
    }
    for (; e + 4 <= s1; e += 4) {
        int i0 = csr[e + slot];
        uint4 q0 = Hb4[(size_t)i0 * 16 + li];
        add8(acc, q0);
    }
    {
        int rem = s1 - e;
        int idx = -1;
        if (slot < rem) idx = csr[e + slot];
        else if (slot == rem) idx = n;          // self-loop row
        if (idx >= 0) {
            uint4 q = Hb4[(size_t)idx * 16 + li];
            add8(acc, q);
        }
    }

#pragma unroll
    for (int j = 0; j < 8; ++j) {
        acc[j] += __shfl_xor(acc[j], 16, 64);
        acc[j] += __shfl_xor(acc[j], 32, 64);
    }

    if (slot < 2) {
        float4 bv = ((const float4*)bias)[li * 2 + slot];
        float o0 = fmaf(dn, acc[4 * slot + 0], bv.x);
        float o1 = fmaf(dn, acc[4 * slot + 1], bv.y);
        float o2 = fmaf(dn, acc[4 * slot + 2], bv.z);
        float o3 = fmaf(dn, acc[4 * slot + 3], bv.w);
        uint2 p;
        p.x = bf16_rne(o0) | (bf16_rne(o1) << 16);
        p.y = bf16_rne(o2) | (bf16_rne(o3) << 16);
        ((uint2*)AGGb)[(size_t)n * 32 + li * 2 + slot] = p;
    }
}

// ====== Aggregate L2 (D=64): 8 edges per wave-instr; fp32 output ======

__global__ __launch_bounds__(256) void k_agg2(
    const int* __restrict__ rowptr, const int* __restrict__ csr,
    const float* __restrict__ dis, const uint4* __restrict__ Hb4,
    const float* __restrict__ bias, float* __restrict__ AGG, int N)
{
    int n = (blockIdx.x * 256 + threadIdx.x) >> 6;
    int lane = threadIdx.x & 63;
    int slot = lane >> 3;        // 0..7
    int li   = lane & 7;         // uint4 index within row (8 * 16B = 128B)
    if (n >= N) return;
    int e = rowptr[n];
    const int s1 = rowptr[n + 1];
    const float dn = dis[n];

    float acc[8];
#pragma unroll
    for (int j = 0; j < 8; ++j) acc[j] = 0.f;

    for (; e + 16 <= s1; e += 16) {
        int i0 = csr[e + slot];
        int i1 = csr[e + 8 + slot];
        uint4 q0 = Hb4[(size_t)i0 * 8 + li];
        uint4 q1 = Hb4[(size_t)i1 * 8 + li];
        add8(acc, q0); add8(acc, q1);
    }
    for (; e + 8 <= s1; e += 8) {
        int i0 = csr[e + slot];
        uint4 q0 = Hb4[(size_t)i0 * 8 + li];
        add8(acc, q0);
    }
    {
        int rem = s1 - e;
        int idx = -1;
        if (slot < rem) idx = csr[e + slot];
        else if (slot == rem) idx = n;
        if (idx >= 0) {
            uint4 q = Hb4[(size_t)idx * 8 + li];
            add8(acc, q);
        }
    }

#pragma unroll
    for (int j = 0; j < 8; ++j) {
        acc[j] += __shfl_xor(acc[j], 8, 64);
        acc[j] += __shfl_xor(acc[j], 16, 64);
        acc[j] += __shfl_xor(acc[j], 32, 64);
    }

    if (slot < 2) {
        float4 bv = ((const float4*)bias)[li * 2 + slot];
        float4 o;
        o.x = fmaf(dn, acc[4 * slot + 0], bv.x);
        o.y = fmaf(dn, acc[4 * slot + 1], bv.y);
        o.z = fmaf(dn, acc[4 * slot + 2], bv.z);
        o.w = fmaf(dn, acc[4 * slot + 3], bv.w);
        ((float4*)AGG)[(size_t)n * 16 + li * 2 + slot] = o;
    }
}

// ================= mean pool over sorted batch =================

__device__ inline int lower_bound(const int* __restrict__ b, int n, int v) {
    int lo = 0, hi = n;
    while (lo < hi) { int m = (lo + hi) >> 1; if (b[m] < v) lo = m + 1; else hi = m; }
    return lo;
}

__global__ __launch_bounds__(256) void k_pool(
    const int* __restrict__ batch, const float* __restrict__ AGG2,
    float* __restrict__ G, int n)
{
    int g = blockIdx.x;
    int start = lower_bound(batch, n, g);
    int end   = lower_bound(batch, n, g + 1);
    int tid = threadIdx.x;
    int f = tid & 63, stripe = tid >> 6;
    float acc = 0.f;
    for (int i = start + stripe; i < end; i += 4)
        acc += AGG2[(size_t)i * 64 + f];
    __shared__ float red[256];
    red[tid] = acc;
    __syncthreads();
    if (tid < 64) {
        float s = red[tid] + red[tid + 64] + red[tid + 128] + red[tid + 192];
        float c = (float)(end - start);
        G[g * 64 + tid] = s / fmaxf(c, 1.0f);
    }
}

// ================= classifier =================

__global__ __launch_bounds__(256) void k_fc(
    const float* __restrict__ G, const float* __restrict__ Wfc,
    const float* __restrict__ bfc, float* __restrict__ out, int ng)
{
    __shared__ float wl[640];
    __shared__ float bl[10];
    int tid = threadIdx.x;
    for (int i = tid; i < 640; i += 256) wl[i] = Wfc[i];
    if (tid < 10) bl[tid] = bfc[tid];
    __syncthreads();
    if (tid >= ng) return;
    float acc[10];
#pragma unroll
    for (int c = 0; c < 10; ++c) acc[c] = bl[c];
    for (int k = 0; k < 64; ++k) {
        float gv = G[tid * 64 + k];
#pragma unroll
        for (int c = 0; c < 10; ++c) acc[c] = fmaf(gv, wl[k * 10 + c], acc[c]);
    }
#pragma unroll
    for (int c = 0; c < 10; ++c) out[tid * 10 + c] = acc[c];
}

// ================= launch =================

extern "C" void kernel_launch(void* const* d_in, const int* in_sizes, int n_in,
                              void* d_out, int out_size, void* d_ws, size_t ws_size,
                              hipStream_t stream)
{
    const float* x    = (const float*)d_in[0];
    const int*   ei   = (const int*)d_in[1];
    const int*   batch= (const int*)d_in[2];
    const float* W1   = (const float*)d_in[3];
    const float* b1   = (const float*)d_in[4];
    const float* W2   = (const float*)d_in[5];
    const float* b2   = (const float*)d_in[6];
    const float* Wfc  = (const float*)d_in[7];
    const float* bfc  = (const float*)d_in[8];
    float* out = (float*)d_out;

    const int N  = in_sizes[0] / 128;     // 100000
    const int E  = in_sizes[1] / 2;       // 3200000
    const int ng = out_size / 10;         // 256

    const int NBK = (N + BKW - 1) / BKW;  // 391 buckets

    // ---- workspace layout (words) ----
    int*   rowptr    = (int*)d_ws;                          // 102400 (N+1)
    int*   bucketCur = rowptr + 102400;                     // 512
    float* dis       = (float*)(bucketCur + 512);           // 102400
    int*   csr       = (int*)(dis + 102400);                // E
    // region A (6.4M words): tmp (NBK*CAP=3.60M) -> Hb1 (N*64) -> agg2 (N*64)
    u32*   tmp       = (u32*)(csr + E);
    u32*   Hb1       = tmp;
    float* agg2      = (float*)tmp;
    u32*   agg1b     = (u32*)((int*)tmp + (size_t)N * 64);      // N*64 u32 (bf16 packed)
    u16*   Hb2       = (u16*)((int*)agg1b + (size_t)N * 128);   // N*64 u16
    float* g         = (float*)((int*)Hb2 + (size_t)N * 32);    // ng*64
    u32*   W1h       = (u32*)(g + (size_t)ng * 64);             // 8192
    u32*   W1l       = W1h + 8192;                              // 8192
    u32*   W2h       = W1l + 8192;                              // 4096
    u32*   W2l       = W2h + 4096;                              // 4096

    // ---- CSR build + weight convert ----
    hipMemsetAsync(bucketCur, 0, NBK * sizeof(int), stream);
    k_convW<<<48, 256, 0, stream>>>(W1, W2, W1h, W1l, W2h, W2l);
    k_part1<<<(E + TILE1 - 1) / TILE1, 512, 0, stream>>>(ei, bucketCur, tmp, E, N, NBK);
    k_part2<<<NBK, 512, 0, stream>>>(bucketCur, tmp, csr, rowptr, dis, N, NBK);

    // ---- layer 1 ----
    k_gemm1m<<<(N + 63) / 64, 256, 0, stream>>>(x, W1h, W1l, dis, Hb1, N);
    k_agg1<<<(N + 3) / 4, 256, 0, stream>>>(rowptr, csr, dis, (const uint4*)Hb1, b1, agg1b, N);

    // ---- layer 2 ----
    k_gemm2m<<<(N + 63) / 64, 256, 0, stream>>>(agg1b, W2h, W2l, dis, (u32*)Hb2, N);
    k_agg2<<<(N + 3) / 4, 256, 0, stream>>>(rowptr, csr, dis, (const uint4*)Hb2, b2, agg2, N);

    // ---- pool + classifier ----
    k_pool<<<ng, 256, 0, stream>>>(batch, agg2, g, N);
    k_fc<<<1, 256, 0, stream>>>(g, Wfc, bfc, out, ng);
}

// Round 13
// 444.575 us; speedup vs baseline: 2.7181x; 1.0190x over previous
//
#include <hip/hip_runtime.h>
#include <math.h>

typedef unsigned int  u32;
typedef unsigned short u16;

#define TILE1 8192      // edges per pass-1 block (16/thread @ 512 threads)
#define BKW   256       // nodes per bucket (shift 8)
#define CAP   9216      // tmp slots per bucket (mean 8192, +11 sigma)

typedef __attribute__((ext_vector_type(8))) short bf16x8;
typedef __attribute__((ext_vector_type(4))) float f32x4;
union frag_u { bf16x8 v; u32 u[4]; uint4 q; };

__device__ inline u32 bf16_rne(float f) {
    u32 u = __float_as_uint(f);
    return (u + 0x7FFFu + ((u >> 16) & 1u)) >> 16;
}
__device__ inline float bf_lo(u32 u) { return __uint_as_float(u << 16); }
__device__ inline float bf_hi(u32 u) { return __uint_as_float(u & 0xFFFF0000u); }

__device__ inline void add8(float* acc, uint4 q) {
    acc[0] += bf_lo(q.x); acc[1] += bf_hi(q.x);
    acc[2] += bf_lo(q.y); acc[3] += bf_hi(q.y);
    acc[4] += bf_lo(q.z); acc[5] += bf_hi(q.z);
    acc[6] += bf_lo(q.w); acc[7] += bf_hi(q.w);
}

// relu on packed bf16x2: clear halves whose sign bit is set
__device__ inline u32 relu_pk(u32 v) {
    u32 s = v & 0x80008000u;
    u32 m = (s >> 15) * 0xFFFFu;
    return v & ~m;
}

// ================= CSR build: 2-pass radix partition =================

__global__ __launch_bounds__(512) void k_part1(const int* __restrict__ ei,
                                               int* __restrict__ bucketCur,
                                               u32* __restrict__ tmp,
                                               int E, int N, int NBK) {
    __shared__ int hist[1024];    // two replicas for count; [0:512) reused as cursor
    __shared__ int base[512];
    const int tid = threadIdx.x;
    if (tid < NBK) { hist[tid] = 0; hist[512 + tid] = 0; }
    __syncthreads();

    const int rep = (tid & 1) << 9;
    const int t0 = blockIdx.x * TILE1;
    int sv[16], dv[16], key[16];
#pragma unroll
    for (int j = 0; j < 16; ++j) {
        int i = t0 + j * 512 + tid;
        key[j] = -1;
        if (i < E) {
            sv[j] = ei[i];
            dv[j] = ei[E + i];
            if ((unsigned)dv[j] < (unsigned)N && (unsigned)sv[j] < (unsigned)N) {
                key[j] = dv[j] >> 8;
                atomicAdd(&hist[key[j] + rep], 1);
            }
        }
    }
    __syncthreads();
    if (tid < NBK) {
        int tot = hist[tid] + hist[512 + tid];
        base[tid] = atomicAdd(&bucketCur[tid], tot);
        hist[tid] = 0;                 // running cursor for placement
    }
    __syncthreads();
#pragma unroll
    for (int j = 0; j < 16; ++j) {
        if (key[j] >= 0) {
            int slot = atomicAdd(&hist[key[j]], 1);
            int off = base[key[j]] + slot;
            if (off < CAP)
                tmp[(size_t)key[j] * CAP + off] =
                    ((u32)(dv[j] & 255) << 17) | (u32)sv[j];
        }
    }
}

__global__ __launch_bounds__(512) void k_part2(const int* __restrict__ bucketCnt,
                                               const u32* __restrict__ tmp,
                                               int* __restrict__ csr,
                                               int* __restrict__ rowptr,
                                               float* __restrict__ dis,
                                               int N, int NBK) {
    __shared__ int hist[256];
    __shared__ int ts[512];
    __shared__ int sStart;
    const int b = blockIdx.x;
    const int t = threadIdx.x;

    int myCnt = (t < NBK) ? bucketCnt[t] : 0;
    ts[t] = myCnt;
    __syncthreads();
    for (int off = 1; off < 512; off <<= 1) {
        int u = (t >= off) ? ts[t - off] : 0;
        __syncthreads();
        ts[t] += u;
        __syncthreads();
    }
    if (t == b) sStart = ts[t] - myCnt;
    if (b == 0 && t == NBK - 1) rowptr[N] = ts[t];
    __syncthreads();
    const int start = sStart;
    const int cnt = bucketCnt[b];
    const u32* src = tmp + (size_t)b * CAP;

    if (t < 256) hist[t] = 0;
    __syncthreads();
    for (int i = t; i < cnt; i += 512)
        atomicAdd(&hist[src[i] >> 17], 1);
    __syncthreads();

    int h = (t < 256) ? hist[t] : 0;
    ts[t] = h;
    __syncthreads();
    for (int off = 1; off < 512; off <<= 1) {
        int u = (t >= off) ? ts[t - off] : 0;
        __syncthreads();
        ts[t] += u;
        __syncthreads();
    }
    if (t < 256) hist[t] = ts[t] - h;       // exclusive
    __syncthreads();

    if (t < 256) {
        int gn = (b << 8) + t;
        if (gn < N) {
            int e0 = hist[t];
            int e1 = (t < 255) ? hist[t + 1] : cnt;
            rowptr[gn] = start + e0;
            dis[gn] = rsqrtf((float)(e1 - e0) + 1.0f);
        }
    }
    __syncthreads();

    for (int i = t; i < cnt; i += 512) {
        u32 v = src[i];
        int p = atomicAdd(&hist[v >> 17], 1);
        csr[start + p] = (int)(v & 0x1FFFFu);
    }
}

// ========== weight convert (+ bucketCur zero): n-major bf16 hi/lo tables ==========

__global__ __launch_bounds__(256) void k_convW(
    const float* __restrict__ W1, const float* __restrict__ W2,
    u32* __restrict__ W1h, u32* __restrict__ W1l,
    u32* __restrict__ W2h, u32* __restrict__ W2l,
    int* __restrict__ bucketCur, int NBK)
{
    int idx = blockIdx.x * 256 + threadIdx.x;
    if (idx < NBK) bucketCur[idx] = 0;
    if (idx < 8192) {
        int n = idx >> 6, k = (idx & 63) * 2;
        float w0 = W1[k * 128 + n], w1 = W1[(k + 1) * 128 + n];
        u32 h0 = bf16_rne(w0), h1 = bf16_rne(w1);
        u32 l0 = bf16_rne(w0 - __uint_as_float(h0 << 16));
        u32 l1 = bf16_rne(w1 - __uint_as_float(h1 << 16));
        W1h[idx] = h0 | (h1 << 16);
        W1l[idx] = l0 | (l1 << 16);
    } else if (idx < 12288) {
        int i2 = idx - 8192;
        int n = i2 >> 6, k = (i2 & 63) * 2;
        float w0 = W2[k * 64 + n], w1 = W2[(k + 1) * 64 + n];
        u32 h0 = bf16_rne(w0), h1 = bf16_rne(w1);
        u32 l0 = bf16_rne(w0 - __uint_as_float(h0 << 16));
        u32 l1 = bf16_rne(w1 - __uint_as_float(h1 << 16));
        W2h[i2] = h0 | (h1 << 16);
        W2l[i2] = l0 | (l1 << 16);
    }
}

// ========== GEMM1 (MFMA): Hb1 = bf16( (X @ W1) * dis ), X fp32 hi/lo split ==========

__global__ __launch_bounds__(256) void k_gemm1m(
    const float* __restrict__ X, const u32* __restrict__ Wh,
    const u32* __restrict__ Wl, const float* __restrict__ dis,
    u32* __restrict__ Hb, int M)
{
    const int w = threadIdx.x >> 6, lane = threadIdx.x & 63;
    const int mrow = blockIdx.x * 64 + w * 16;
    if (mrow >= M) return;
    const int m16 = lane & 15, quad = lane >> 4;
    int gm = mrow + m16; if (gm >= M) gm = M - 1;

    frag_u Ah[4], Al[4];
    const float* xr = X + (size_t)gm * 128;
#pragma unroll
    for (int kt = 0; kt < 4; ++kt) {
        int kb = kt * 32 + quad * 8;
        float4 xa = *(const float4*)(xr + kb);
        float4 xb = *(const float4*)(xr + kb + 4);
        float xe[8] = {xa.x, xa.y, xa.z, xa.w, xb.x, xb.y, xb.z, xb.w};
#pragma unroll
        for (int j = 0; j < 4; ++j) {
            u32 h0 = bf16_rne(xe[2 * j]),     h1 = bf16_rne(xe[2 * j + 1]);
            u32 l0 = bf16_rne(xe[2 * j]     - __uint_as_float(h0 << 16));
            u32 l1 = bf16_rne(xe[2 * j + 1] - __uint_as_float(h1 << 16));
            Ah[kt].u[j] = h0 | (h1 << 16);
            Al[kt].u[j] = l0 | (l1 << 16);
        }
    }

    float dv[4];
#pragma unroll
    for (int r = 0; r < 4; ++r) {
        int gR = mrow + quad * 4 + r;
        dv[r] = (gR < M) ? dis[gR] : 0.f;
    }

    const uint4* Wh4 = (const uint4*)Wh;
    const uint4* Wl4 = (const uint4*)Wl;
#pragma unroll
    for (int nt = 0; nt < 8; ++nt) {
        f32x4 acc = {0.f, 0.f, 0.f, 0.f};
        int nrow = nt * 16 + m16;
#pragma unroll
        for (int kt = 0; kt < 4; ++kt) {
            frag_u Bh, Bl;
            Bh.q = Wh4[nrow * 16 + kt * 4 + quad];
            Bl.q = Wl4[nrow * 16 + kt * 4 + quad];
            acc = __builtin_amdgcn_mfma_f32_16x16x32_bf16(Al[kt].v, Bh.v, acc, 0, 0, 0);
            acc = __builtin_amdgcn_mfma_f32_16x16x32_bf16(Ah[kt].v, Bl.v, acc, 0, 0, 0);
            acc = __builtin_amdgcn_mfma_f32_16x16x32_bf16(Ah[kt].v, Bh.v, acc, 0, 0, 0);
        }
#pragma unroll
        for (int r = 0; r < 4; ++r) {
            float vs = acc[r] * dv[r];
            float vo = __shfl_xor(vs, 1, 64);
            if ((m16 & 1) == 0) {
                int gR = mrow + quad * 4 + r;
                if (gR < M)
                    Hb[(size_t)gR * 64 + nt * 8 + (m16 >> 1)] =
                        bf16_rne(vs) | (bf16_rne(vo) << 16);
            }
        }
    }
}

// ========== GEMM2 (MFMA): Hb2 = bf16( (relu(agg1b) @ W2) * dis ) ==========

__global__ __launch_bounds__(256) void k_gemm2m(
    const u32* __restrict__ Xb, const u32* __restrict__ Wh,
    const u32* __restrict__ Wl, const float* __restrict__ dis,
    u32* __restrict__ Hb, int M)
{
    const int w = threadIdx.x >> 6, lane = threadIdx.x & 63;
    const int mrow = blockIdx.x * 64 + w * 16;
    if (mrow >= M) return;
    const int m16 = lane & 15, quad = lane >> 4;
    int gm = mrow + m16; if (gm >= M) gm = M - 1;

    const uint4* X4 = (const uint4*)Xb;
    frag_u A[4];
#pragma unroll
    for (int kt = 0; kt < 4; ++kt) {
        A[kt].q = X4[(size_t)gm * 16 + kt * 4 + quad];
#pragma unroll
        for (int j = 0; j < 4; ++j) A[kt].u[j] = relu_pk(A[kt].u[j]);
    }

    float dv[4];
#pragma unroll
    for (int r = 0; r < 4; ++r) {
        int gR = mrow + quad * 4 + r;
        dv[r] = (gR < M) ? dis[gR] : 0.f;
    }

    const uint4* Wh4 = (const uint4*)Wh;
    const uint4* Wl4 = (const uint4*)Wl;
#pragma unroll
    for (int nt = 0; nt < 4; ++nt) {
        f32x4 acc = {0.f, 0.f, 0.f, 0.f};
        int nrow = nt * 16 + m16;
#pragma unroll
        for (int kt = 0; kt < 4; ++kt) {
            frag_u Bh, Bl;
            Bh.q = Wh4[nrow * 16 + kt * 4 + quad];
            Bl.q = Wl4[nrow * 16 + kt * 4 + quad];
            acc = __builtin_amdgcn_mfma_f32_16x16x32_bf16(A[kt].v, Bl.v, acc, 0, 0, 0);
            acc = __builtin_amdgcn_mfma_f32_16x16x32_bf16(A[kt].v, Bh.v, acc, 0, 0, 0);
        }
#pragma unroll
        for (int r = 0; r < 4; ++r) {
            float vs = acc[r] * dv[r];
            float vo = __shfl_xor(vs, 1, 64);
            if ((m16 & 1) == 0) {
                int gR = mrow + quad * 4 + r;
                if (gR < M)
                    Hb[(size_t)gR * 32 + nt * 8 + (m16 >> 1)] =
                        bf16_rne(vs) | (bf16_rne(vo) << 16);
            }
        }
    }
}

// ====== Aggregate L1 (D=128): wave per node, 4 edges per wave-instr; bf16 out ======

__global__ __launch_bounds__(256) void k_agg1(
    const int* __restrict__ rowptr, const int* __restrict__ csr,
    const float* __restrict__ dis, const uint4* __restrict__ Hb4,
    const float* __restrict__ bias, u32* __restrict__ AGGb, int N)
{
    int n = (blockIdx.x * 256 + threadIdx.x) >> 6;
    int lane = threadIdx.x & 63;
    int slot = lane >> 4;        // 0..3
    int li   = lane & 15;        // uint4 index within row (16 * 16B = 256B)
    if (n >= N) return;
    int e = rowptr[n];
    const int s1 = rowptr[n + 1];
    const float dn = dis[n];

    float acc[8];
#pragma unroll
    for (int j = 0; j < 8; ++j) acc[j] = 0.f;

    for (; e + 16 <= s1; e += 16) {
        int i0 = csr[e + slot];
        int i1 = csr[e + 4 + slot];
        int i2 = csr[e + 8 + slot];
        int i3 = csr[e + 12 + slot];
        uint4 q0 = Hb4[(size_t)i0 * 16 + li];
        uint4 q1 = Hb4[(size_t)i1 * 16 + li];
        uint4 q2 = Hb4[(size_t)i2 * 16 + li];
        uint4 q3 = Hb4[(size_t)i3 * 16 + li];
        add8(acc, q0); add8(acc, q1); add8(acc, q2); add8(acc, q3);
    }
    for (; e + 4 <= s1; e += 4) {
        int i0 = csr[e + slot];
        uint4 q0 = Hb4[(size_t)i0 * 16 + li];
        add8(acc, q0);
    }
    {
        int rem = s1 - e;
        int idx = -1;
        if (slot < rem) idx = csr[e + slot];
        else if (slot == rem) idx = n;          // self-loop row
        if (idx >= 0) {
            uint4 q = Hb4[(size_t)idx * 16 + li];
            add8(acc, q);
        }
    }

#pragma unroll
    for (int j = 0; j < 8; ++j) {
        acc[j] += __shfl_xor(acc[j], 16, 64);
        acc[j] += __shfl_xor(acc[j], 32, 64);
    }

    if (slot < 2) {
        float4 bv = ((const float4*)bias)[li * 2 + slot];
        float o0 = fmaf(dn, acc[4 * slot + 0], bv.x);
        float o1 = fmaf(dn, acc[4 * slot + 1], bv.y);
        float o2 = fmaf(dn, acc[4 * slot + 2], bv.z);
        float o3 = fmaf(dn, acc[4 * slot + 3], bv.w);
        uint2 p;
        p.x = bf16_rne(o0) | (bf16_rne(o1) << 16);
        p.y = bf16_rne(o2) | (bf16_rne(o3) << 16);
        ((uint2*)AGGb)[(size_t)n * 32 + li * 2 + slot] = p;
    }
}

// ====== Aggregate L2 (D=64): 8 edges per wave-instr; packed bf16 out ======

__global__ __launch_bounds__(256) void k_agg2(
    const int* __restrict__ rowptr, const int* __restrict__ csr,
    const float* __restrict__ dis, const uint4* __restrict__ Hb4,
    const float* __restrict__ bias, u32* __restrict__ AGGb, int N)
{
    int n = (blockIdx.x * 256 + threadIdx.x) >> 6;
    int lane = threadIdx.x & 63;
    int slot = lane >> 3;        // 0..7
    int li   = lane & 7;         // uint4 index within row (8 * 16B = 128B)
    if (n >= N) return;
    int e = rowptr[n];
    const int s1 = rowptr[n + 1];
    const float dn = dis[n];

    float acc[8];
#pragma unroll
    for (int j = 0; j < 8; ++j) acc[j] = 0.f;

    for (; e + 16 <= s1; e += 16) {
        int i0 = csr[e + slot];
        int i1 = csr[e + 8 + slot];
        uint4 q0 = Hb4[(size_t)i0 * 8 + li];
        uint4 q1 = Hb4[(size_t)i1 * 8 + li];
        add8(acc, q0); add8(acc, q1);
    }
    for (; e + 8 <= s1; e += 8) {
        int i0 = csr[e + slot];
        uint4 q0 = Hb4[(size_t)i0 * 8 + li];
        add8(acc, q0);
    }
    {
        int rem = s1 - e;
        int idx = -1;
        if (slot < rem) idx = csr[e + slot];
        else if (slot == rem) idx = n;
        if (idx >= 0) {
            uint4 q = Hb4[(size_t)idx * 8 + li];
            add8(acc, q);
        }
    }

#pragma unroll
    for (int j = 0; j < 8; ++j) {
        acc[j] += __shfl_xor(acc[j], 8, 64);
        acc[j] += __shfl_xor(acc[j], 16, 64);
        acc[j] += __shfl_xor(acc[j], 32, 64);
    }

    // slot s<2 holds cols [8li+4s, 8li+4s+4) -> uint2 index 2li+s
    if (slot < 2) {
        float4 bv = ((const float4*)bias)[li * 2 + slot];
        float o0 = fmaf(dn, acc[4 * slot + 0], bv.x);
        float o1 = fmaf(dn, acc[4 * slot + 1], bv.y);
        float o2 = fmaf(dn, acc[4 * slot + 2], bv.z);
        float o3 = fmaf(dn, acc[4 * slot + 3], bv.w);
        uint2 p;
        p.x = bf16_rne(o0) | (bf16_rne(o1) << 16);
        p.y = bf16_rne(o2) | (bf16_rne(o3) << 16);
        ((uint2*)AGGb)[(size_t)n * 16 + li * 2 + slot] = p;
    }
}

// ========= mean pool over sorted batch (bf16 input) + fused classifier =========

__device__ inline int lower_bound(const int* __restrict__ b, int n, int v) {
    int lo = 0, hi = n;
    while (lo < hi) { int m = (lo + hi) >> 1; if (b[m] < v) lo = m + 1; else hi = m; }
    return lo;
}

__global__ __launch_bounds__(256) void k_poolfc(
    const int* __restrict__ batch, const u32* __restrict__ AGGb2,
    const float* __restrict__ Wfc, const float* __restrict__ bfc,
    float* __restrict__ out, int n)
{
    int g = blockIdx.x;
    int start = lower_bound(batch, n, g);
    int end   = lower_bound(batch, n, g + 1);
    int tid = threadIdx.x;
    int f = tid & 63, stripe = tid >> 6;
    int ui = f >> 1, hi = f & 1;
    float acc = 0.f;
    for (int i = start + stripe; i < end; i += 4) {
        u32 v = AGGb2[(size_t)i * 32 + ui];
        acc += hi ? bf_hi(v) : bf_lo(v);
    }
    __shared__ float red[256];
    __shared__ float mean[64];
    red[tid] = acc;
    __syncthreads();
    if (tid < 64) {
        float s = red[tid] + red[tid + 64] + red[tid + 128] + red[tid + 192];
        float c = (float)(end - start);
        mean[tid] = s / fmaxf(c, 1.0f);
    }
    __syncthreads();
    if (tid < 10) {
        float o = bfc[tid];
        for (int k = 0; k < 64; ++k)
            o = fmaf(mean[k], Wfc[k * 10 + tid], o);
        out[g * 10 + tid] = o;
    }
}

// ================= launch =================

extern "C" void kernel_launch(void* const* d_in, const int* in_sizes, int n_in,
                              void* d_out, int out_size, void* d_ws, size_t ws_size,
                              hipStream_t stream)
{
    const float* x    = (const float*)d_in[0];
    const int*   ei   = (const int*)d_in[1];
    const int*   batch= (const int*)d_in[2];
    const float* W1   = (const float*)d_in[3];
    const float* b1   = (const float*)d_in[4];
    const float* W2   = (const float*)d_in[5];
    const float* b2   = (const float*)d_in[6];
    const float* Wfc  = (const float*)d_in[7];
    const float* bfc  = (const float*)d_in[8];
    float* out = (float*)d_out;

    const int N  = in_sizes[0] / 128;     // 100000
    const int E  = in_sizes[1] / 2;       // 3200000
    const int ng = out_size / 10;         // 256

    const int NBK = (N + BKW - 1) / BKW;  // 391 buckets

    // ---- workspace layout (words) ----
    int*   rowptr    = (int*)d_ws;                          // 102400 (N+1)
    int*   bucketCur = rowptr + 102400;                     // 512
    float* dis       = (float*)(bucketCur + 512);           // 102400
    int*   csr       = (int*)(dis + 102400);                // E
    // region A (6.4M words): tmp (NBK*CAP=3.60M) -> Hb1 (N*64) -> agg2b (N*32)
    u32*   tmp       = (u32*)(csr + E);
    u32*   Hb1       = tmp;
    u32*   agg2b     = tmp;
    u32*   agg1b     = (u32*)((int*)tmp + (size_t)N * 64);      // N*64 u32 (bf16 packed)
    u16*   Hb2       = (u16*)((int*)agg1b + (size_t)N * 128);   // N*64 u16
    u32*   W1h       = (u32*)((int*)Hb2 + (size_t)N * 32);      // 8192
    u32*   W1l       = W1h + 8192;                              // 8192
    u32*   W2h       = W1l + 8192;                              // 4096
    u32*   W2l       = W2h + 4096;                              // 4096

    // ---- weight convert (+ bucketCur zero) + CSR build ----
    k_convW<<<48, 256, 0, stream>>>(W1, W2, W1h, W1l, W2h, W2l, bucketCur, NBK);
    k_part1<<<(E + TILE1 - 1) / TILE1, 512, 0, stream>>>(ei, bucketCur, tmp, E, N, NBK);
    k_part2<<<NBK, 512, 0, stream>>>(bucketCur, tmp, csr, rowptr, dis, N, NBK);

    // ---- layer 1 ----
    k_gemm1m<<<(N + 63) / 64, 256, 0, stream>>>(x, W1h, W1l, dis, Hb1, N);
    k_agg1<<<(N + 3) / 4, 256, 0, stream>>>(rowptr, csr, dis, (const uint4*)Hb1, b1, agg1b, N);

    // ---- layer 2 ----
    k_gemm2m<<<(N + 63) / 64, 256, 0, stream>>>(agg1b, W2h, W2l, dis, (u32*)Hb2, N);
    k_agg2<<<(N + 3) / 4, 256, 0, stream>>>(rowptr, csr, dis, (const uint4*)Hb2, b2, agg2b, N);

    // ---- pool + classifier (fused) ----
    k_poolfc<<<ng, 256, 0, stream>>>(batch, agg2b, Wfc, bfc, out, N);
}